// Round 1
// baseline (20649.506 us; speedup 1.0000x reference)
//
#include <hip/hip_runtime.h>
#include <math.h>

#define NPTS 8192
#define PPC  1024
#define BCL  8
#define KNN  20
#define HDIM 256
#define HD2  512
#define NL   3
#define NCOMP 512
#define EDG  (NPTS*KNN)

// ---------------- KNN: per-thread top-20 insertion over own cloud ----------------
__global__ __launch_bounds__(256)
void knn_kernel(const float* __restrict__ pos, int* __restrict__ neigh, float* __restrict__ rel) {
  int i = blockIdx.x * 256 + threadIdx.x;
  if (i >= NPTS) return;
  int base = (i >> 10) << 10;  // cloud start
  float xi = pos[i*3+0], yi = pos[i*3+1], zi = pos[i*3+2];
  float bd[KNN]; int bi[KNN];
  #pragma unroll
  for (int k = 0; k < KNN; ++k) { bd[k] = 3.4e38f; bi[k] = -1; }
  for (int j = base; j < base + PPC; ++j) {
    if (j == i) continue;
    float dx = xi - pos[j*3+0];
    float dy = yi - pos[j*3+1];
    float dz = zi - pos[j*3+2];
    float d2 = dx*dx + dy*dy + dz*dz;
    if (d2 < bd[KNN-1]) {        // strict <  => earlier index wins ties (matches top_k)
      float cd = d2; int ci = j;
      #pragma unroll
      for (int k = 0; k < KNN; ++k) {
        if (cd < bd[k]) {
          float td = bd[k]; int ti = bi[k];
          bd[k] = cd; bi[k] = ci; cd = td; ci = ti;
        }
      }
    }
  }
  #pragma unroll
  for (int k = 0; k < KNN; ++k) {
    int j = bi[k];
    neigh[(size_t)i*KNN + k] = j;
    size_t r = ((size_t)i*KNN + k) * 3;
    rel[r+0] = xi - pos[j*3+0];
    rel[r+1] = yi - pos[j*3+1];
    rel[r+2] = zi - pos[j*3+2];
  }
}

// ---------------- fp32 tiled GEMM: C[M,N] = A[M,K] @ B[K,N] (+bias) ----------------
// 64x64 tile, BK=16, 256 threads, 4x4 per-thread micro-tile. Bounds-checked & K zero-padded.
#define BM 64
#define BN 64
#define BK 16
__global__ __launch_bounds__(256)
void gemm_bias(const float* __restrict__ A, const float* __restrict__ Bw,
               const float* __restrict__ bias, float* __restrict__ C,
               int M, int Nn, int Kk) {
  __shared__ float As[BK][BM+1];
  __shared__ float Bs[BK][BN+1];
  int bm = blockIdx.y * BM;
  int bn = blockIdx.x * BN;
  int tid = threadIdx.x;
  int tx = tid & 15;   // N dir
  int ty = tid >> 4;   // M dir
  float acc[4][4] = {{0.f}};
  for (int k0 = 0; k0 < Kk; k0 += BK) {
    #pragma unroll
    for (int ii = 0; ii < 4; ++ii) {
      int e = tid + ii * 256;
      int m = e >> 4, k = e & 15;
      int gm = bm + m, gk = k0 + k;
      float va = 0.f;
      if (gm < M && gk < Kk) va = A[(size_t)gm * Kk + gk];
      As[k][m] = va;
    }
    #pragma unroll
    for (int ii = 0; ii < 4; ++ii) {
      int e = tid + ii * 256;
      int k = e >> 6, n = e & 63;
      int gk = k0 + k, gn = bn + n;
      float vb = 0.f;
      if (gk < Kk && gn < Nn) vb = Bw[(size_t)gk * Nn + gn];
      Bs[k][n] = vb;
    }
    __syncthreads();
    #pragma unroll
    for (int kk = 0; kk < BK; ++kk) {
      float a[4], b[4];
      #pragma unroll
      for (int ii = 0; ii < 4; ++ii) a[ii] = As[kk][ty*4+ii];
      #pragma unroll
      for (int jj = 0; jj < 4; ++jj) b[jj] = Bs[kk][tx*4+jj];
      #pragma unroll
      for (int ii = 0; ii < 4; ++ii)
        #pragma unroll
        for (int jj = 0; jj < 4; ++jj)
          acc[ii][jj] += a[ii] * b[jj];
    }
    __syncthreads();
  }
  #pragma unroll
  for (int ii = 0; ii < 4; ++ii) {
    int gm = bm + ty*4 + ii;
    if (gm >= M) continue;
    #pragma unroll
    for (int jj = 0; jj < 4; ++jj) {
      int gn = bn + tx*4 + jj;
      if (gn >= Nn) continue;
      float vv = acc[ii][jj];
      if (bias) vv += bias[gn];
      C[(size_t)gm * Nn + gn] = vv;
    }
  }
}

// ---------------- LayerNorm (+optional ELU), rows of Cn in {256,512}, in-place safe ----------------
__global__ __launch_bounds__(256)
void ln_elu_kernel(const float* __restrict__ in, float* __restrict__ out,
                   const float* __restrict__ g, const float* __restrict__ bb,
                   int Cn, int do_elu) {
  __shared__ float sdata[4];
  size_t row = blockIdx.x;
  const float* x = in + row * Cn;
  float* y = out + row * Cn;
  int tid = threadIdx.x;
  float v0 = x[tid];
  float v1 = (Cn == 512) ? x[tid + 256] : 0.f;
  float s = v0 + v1;
  #pragma unroll
  for (int off = 32; off > 0; off >>= 1) s += __shfl_xor(s, off, 64);
  if ((tid & 63) == 0) sdata[tid >> 6] = s;
  __syncthreads();
  float tot = sdata[0] + sdata[1] + sdata[2] + sdata[3];
  float mean = tot / (float)Cn;
  float d0 = v0 - mean;
  float d1 = (Cn == 512) ? (v1 - mean) : 0.f;
  float sq = d0*d0 + d1*d1;
  __syncthreads();
  #pragma unroll
  for (int off = 32; off > 0; off >>= 1) sq += __shfl_xor(sq, off, 64);
  if ((tid & 63) == 0) sdata[tid >> 6] = sq;
  __syncthreads();
  float var = (sdata[0] + sdata[1] + sdata[2] + sdata[3]) / (float)Cn;
  float r = rsqrtf(var + 1e-5f);
  float y0 = d0 * r * g[tid] + bb[tid];
  if (do_elu) y0 = (y0 > 0.f) ? y0 : (expf(y0) - 1.f);
  y[tid] = y0;
  if (Cn == 512) {
    float y1 = d1 * r * g[tid+256] + bb[tid+256];
    if (do_elu) y1 = (y1 > 0.f) ? y1 : (expf(y1) - 1.f);
    y[tid + 256] = y1;
  }
}

// ---------------- attn-MLP input: t[e,c] = a_dst[i,c] - a_src[j,c] + delta[e,c] ----------------
__global__ __launch_bounds__(256)
void build_attn_in(const float* __restrict__ a_dst, const float* __restrict__ a_src,
                   const float* __restrict__ delta_c, const int* __restrict__ neigh,
                   float* __restrict__ t_c, int node0) {
  int e_local = blockIdx.x;
  int c = threadIdx.x;
  int i = node0 + e_local / KNN;
  int j = neigh[(size_t)node0 * KNN + e_local];
  t_c[(size_t)e_local * HDIM + c] =
      a_dst[(size_t)i * HDIM + c] - a_src[(size_t)j * HDIM + c] + delta_c[(size_t)e_local * HDIM + c];
}

// ---------------- per-channel softmax over K + weighted aggregation ----------------
__global__ __launch_bounds__(256)
void softmax_agg(const float* __restrict__ alpha_c, const float* __restrict__ delta_c,
                 const float* __restrict__ v, const int* __restrict__ neigh,
                 float* __restrict__ agg, int node0) {
  int nl = blockIdx.x;
  int c = threadIdx.x;
  int i = node0 + nl;
  float av[KNN];
  float mx = -3.4e38f;
  #pragma unroll
  for (int k = 0; k < KNN; ++k) {
    av[k] = alpha_c[((size_t)nl * KNN + k) * HDIM + c];
    mx = fmaxf(mx, av[k]);
  }
  float ssum = 0.f;
  #pragma unroll
  for (int k = 0; k < KNN; ++k) { av[k] = expf(av[k] - mx); ssum += av[k]; }
  float inv = 1.f / ssum;
  float acc = 0.f;
  #pragma unroll
  for (int k = 0; k < KNN; ++k) {
    int j = neigh[(size_t)i * KNN + k];
    acc += av[k] * inv * (v[(size_t)j * HDIM + c] + delta_c[((size_t)nl * KNN + k) * HDIM + c]);
  }
  agg[(size_t)i * HDIM + c] = acc;
}

// ---------------- x += res_alpha[l] * h ----------------
__global__ __launch_bounds__(256)
void axpy_res(float* __restrict__ x, const float* __restrict__ h,
              const float* __restrict__ alpha, int l) {
  size_t idx = (size_t)blockIdx.x * 256 + threadIdx.x;
  x[idx] += alpha[l] * h[idx];
}

// ---------------- global max pool per cloud ----------------
__global__ __launch_bounds__(256)
void seg_max(const float* __restrict__ h, float* __restrict__ pooled) {
  int b = blockIdx.x;
  int c = threadIdx.x;
  float m = -3.4e38f;
  for (int p = 0; p < PPC; ++p)
    m = fmaxf(m, h[((size_t)(b * PPC + p)) * HDIM + c]);
  pooled[(size_t)b * HDIM + c] = m;
}

extern "C" void kernel_launch(void* const* d_in, const int* in_sizes, int n_in,
                              void* d_out, int out_size, void* d_ws, size_t ws_size,
                              hipStream_t stream) {
  const float* pos       = (const float*)d_in[0];
  const float* ffm_W     = (const float*)d_in[2];
  const float* ffm_b     = (const float*)d_in[3];
  const float* lin_W     = (const float*)d_in[4];
  const float* src_W     = (const float*)d_in[5];
  const float* dst_W     = (const float*)d_in[6];
  const float* pos1_W    = (const float*)d_in[7];
  const float* pos1_b    = (const float*)d_in[8];
  const float* pos_ln1_g = (const float*)d_in[9];
  const float* pos_ln1_b = (const float*)d_in[10];
  const float* pos2_W    = (const float*)d_in[11];
  const float* pos2_b    = (const float*)d_in[12];
  const float* pos_ln2_g = (const float*)d_in[13];
  const float* pos_ln2_b = (const float*)d_in[14];
  const float* att1_W    = (const float*)d_in[15];
  const float* att1_b    = (const float*)d_in[16];
  const float* att_ln1_g = (const float*)d_in[17];
  const float* att_ln1_b = (const float*)d_in[18];
  const float* att2_W    = (const float*)d_in[19];
  const float* att2_b    = (const float*)d_in[20];
  const float* att_ln2_g = (const float*)d_in[21];
  const float* att_ln2_b = (const float*)d_in[22];
  const float* blk_ln_g  = (const float*)d_in[23];
  const float* blk_ln_b  = (const float*)d_in[24];
  const float* blk_W     = (const float*)d_in[25];
  const float* blk_b     = (const float*)d_in[26];
  const float* res_alpha = (const float*)d_in[27];
  const float* r1_W = (const float*)d_in[28]; const float* r1_b = (const float*)d_in[29];
  const float* r2_W = (const float*)d_in[30]; const float* r2_b = (const float*)d_in[31];
  const float* r2_ln_g = (const float*)d_in[32]; const float* r2_ln_b = (const float*)d_in[33];
  const float* r3_W = (const float*)d_in[34]; const float* r3_b = (const float*)d_in[35];
  const float* r3_ln_g = (const float*)d_in[36]; const float* r3_ln_b = (const float*)d_in[37];
  const float* r4_W = (const float*)d_in[38]; const float* r4_b = (const float*)d_in[39];
  float* out = (float*)d_out;

  // ---- workspace carve-up (all sizes 16B-aligned by construction) ----
  char* wsp = (char*)d_ws;
  auto allocf = [&](size_t nfloats) -> float* {
    float* p = (float*)wsp; wsp += nfloats * sizeof(float); return p;
  };
  int*   neigh  = (int*)allocf(EDG);
  float* rel    = allocf((size_t)EDG * 3);
  float* x      = allocf((size_t)NPTS * HDIM);
  float* a_src  = allocf((size_t)NPTS * HDIM);
  float* a_dst  = allocf((size_t)NPTS * HDIM);
  float* v      = allocf((size_t)NPTS * HDIM);
  float* agg    = allocf((size_t)NPTS * HDIM);
  float* pooled = allocf((size_t)BCL * HDIM);
  float* hh     = allocf((size_t)BCL * HDIM);

  // chunk the edge dimension by available workspace
  size_t used    = (size_t)(wsp - (char*)d_ws);
  size_t avail_f = (ws_size > used) ? (ws_size - used) / sizeof(float) : 0;
  size_t per_node = (size_t)KNN * (HDIM + HDIM + HD2);   // delta + t/alpha + hid
  int Nc = (int)(avail_f / per_node);
  if (Nc > NPTS) Nc = NPTS;
  Nc &= ~15;
  if (Nc < 16) Nc = 16;   // minimal fallback
  float* delta_c = allocf((size_t)Nc * KNN * HDIM);
  float* t_c     = allocf((size_t)Nc * KNN * HDIM);
  float* hid_c   = allocf((size_t)Nc * KNN * HD2);

  auto gemm = [&](const float* A, const float* Bw, const float* bias, float* Cp,
                  int M, int Nn, int Kk) {
    dim3 g((Nn + BN - 1) / BN, (M + BM - 1) / BM);
    gemm_bias<<<g, dim3(256), 0, stream>>>(A, Bw, bias, Cp, M, Nn, Kk);
  };

  // ---- graph + stem ----
  knn_kernel<<<NPTS / 256, 256, 0, stream>>>(pos, neigh, rel);
  gemm(pos, ffm_W, ffm_b, x, NPTS, HDIM, 3);

  // ---- transformer layers ----
  for (int l = 0; l < NL; ++l) {
    gemm(x, src_W + (size_t)l * HDIM * HDIM, nullptr, a_src, NPTS, HDIM, HDIM);
    gemm(x, dst_W + (size_t)l * HDIM * HDIM, nullptr, a_dst, NPTS, HDIM, HDIM);
    gemm(x, lin_W + (size_t)l * HDIM * HDIM, nullptr, v,     NPTS, HDIM, HDIM);

    for (int n0 = 0; n0 < NPTS; n0 += Nc) {
      int nc = (Nc < NPTS - n0) ? Nc : (NPTS - n0);
      int ec = nc * KNN;
      // pos_nn: rel -> hid(512) -> LN+ELU -> delta(256) -> LN+ELU
      gemm(rel + (size_t)n0 * KNN * 3, pos1_W + (size_t)l * 3 * HD2, pos1_b + (size_t)l * HD2,
           hid_c, ec, HD2, 3);
      ln_elu_kernel<<<ec, 256, 0, stream>>>(hid_c, hid_c, pos_ln1_g + (size_t)l * HD2,
                                            pos_ln1_b + (size_t)l * HD2, HD2, 1);
      gemm(hid_c, pos2_W + (size_t)l * HD2 * HDIM, pos2_b + (size_t)l * HDIM,
           delta_c, ec, HDIM, HD2);
      ln_elu_kernel<<<ec, 256, 0, stream>>>(delta_c, delta_c, pos_ln2_g + (size_t)l * HDIM,
                                            pos_ln2_b + (size_t)l * HDIM, HDIM, 1);
      // attn_nn input, then MLP -> alpha (reuses t_c)
      build_attn_in<<<ec, 256, 0, stream>>>(a_dst, a_src, delta_c, neigh, t_c, n0);
      gemm(t_c, att1_W + (size_t)l * HDIM * HD2, att1_b + (size_t)l * HD2, hid_c, ec, HD2, HDIM);
      ln_elu_kernel<<<ec, 256, 0, stream>>>(hid_c, hid_c, att_ln1_g + (size_t)l * HD2,
                                            att_ln1_b + (size_t)l * HD2, HD2, 1);
      gemm(hid_c, att2_W + (size_t)l * HD2 * HDIM, att2_b + (size_t)l * HDIM, t_c, ec, HDIM, HD2);
      ln_elu_kernel<<<ec, 256, 0, stream>>>(t_c, t_c, att_ln2_g + (size_t)l * HDIM,
                                            att_ln2_b + (size_t)l * HDIM, HDIM, 1);
      // per-channel softmax over K + aggregate
      softmax_agg<<<nc, 256, 0, stream>>>(t_c, delta_c, v, neigh, agg, n0);
    }
    // tail: elu(LN(agg)) @ blk_W + blk_b, residual-add
    ln_elu_kernel<<<NPTS, 256, 0, stream>>>(agg, a_src, blk_ln_g + (size_t)l * HDIM,
                                            blk_ln_b + (size_t)l * HDIM, HDIM, 1);
    gemm(a_src, blk_W + (size_t)l * HDIM * HDIM, blk_b + (size_t)l * HDIM, a_dst, NPTS, HDIM, HDIM);
    axpy_res<<<(NPTS * HDIM) / 256, 256, 0, stream>>>(x, a_dst, res_alpha, l);
  }

  // ---- regression head ----
  gemm(x, r1_W, r1_b, agg, NPTS, HDIM, HDIM);
  seg_max<<<BCL, 256, 0, stream>>>(agg, pooled);
  gemm(pooled, r2_W, r2_b, hh, BCL, HDIM, HDIM);
  ln_elu_kernel<<<BCL, 256, 0, stream>>>(hh, hh, r2_ln_g, r2_ln_b, HDIM, 1);
  gemm(hh, r3_W, r3_b, pooled, BCL, HDIM, HDIM);
  ln_elu_kernel<<<BCL, 256, 0, stream>>>(pooled, pooled, r3_ln_g, r3_ln_b, HDIM, 1);
  gemm(pooled, r4_W, r4_b, out, BCL, NCOMP, HDIM);
}

// Round 2
// 4498.731 us; speedup vs baseline: 4.5901x; 4.5901x over previous
//
#include <hip/hip_runtime.h>
#include <math.h>

#define NPTS 8192
#define PPC  1024
#define BCL  8
#define KNN  20
#define HDIM 256
#define HD2  512
#define NL   3
#define NCOMP 512
#define EDG  (NPTS*KNN)

typedef __bf16 bf16x8 __attribute__((ext_vector_type(8)));
typedef float f32x4 __attribute__((ext_vector_type(4)));
typedef unsigned int uint4v __attribute__((ext_vector_type(4)));

__device__ inline unsigned short f2bf(float f) {
  unsigned u = __float_as_uint(f);
  u += 0x7FFF + ((u >> 16) & 1);   // RNE
  return (unsigned short)(u >> 16);
}

// ---------------- KNN: one block per point, LDS distance array + 20x parallel argmin ----------------
__global__ __launch_bounds__(256)
void knn_block(const float* __restrict__ pos, int* __restrict__ neigh,
               unsigned short* __restrict__ rel_b) {
  __shared__ float px[PPC], py[PPC], pz[PPC];
  __shared__ float dist[PPC];
  __shared__ float wv[4]; __shared__ int wi[4];
  __shared__ int bidx[KNN];
  int i = blockIdx.x;
  int base = i & ~(PPC - 1);
  int tid = threadIdx.x;
  for (int t = tid; t < PPC; t += 256) {
    px[t] = pos[(size_t)(base + t) * 3 + 0];
    py[t] = pos[(size_t)(base + t) * 3 + 1];
    pz[t] = pos[(size_t)(base + t) * 3 + 2];
  }
  __syncthreads();
  float xi = px[i - base], yi = py[i - base], zi = pz[i - base];
  for (int t = tid; t < PPC; t += 256) {
    float dx = xi - px[t], dy = yi - py[t], dz = zi - pz[t];
    float d2 = dx * dx + dy * dy + dz * dz;
    dist[t] = (base + t == i) ? 3.4e38f : d2;
  }
  __syncthreads();
  int lane = tid & 63, wave = tid >> 6;
  for (int k = 0; k < KNN; ++k) {
    // local argmin over 4 contiguous elements (ascending index => lowest-index tie-break)
    int id = tid * 4;
    float v = dist[id];
    #pragma unroll
    for (int q = 1; q < 4; ++q) {
      float d = dist[tid * 4 + q];
      if (d < v) { v = d; id = tid * 4 + q; }
    }
    // wave butterfly argmin, tie -> lower index
    #pragma unroll
    for (int off = 1; off < 64; off <<= 1) {
      float ov = __shfl_xor(v, off, 64);
      int oi = __shfl_xor(id, off, 64);
      if (ov < v || (ov == v && oi < id)) { v = ov; id = oi; }
    }
    if (lane == 0) { wv[wave] = v; wi[wave] = id; }
    __syncthreads();
    if (tid == 0) {
      float bv = wv[0]; int bi = wi[0];
      #pragma unroll
      for (int w = 1; w < 4; ++w)
        if (wv[w] < bv || (wv[w] == bv && wi[w] < bi)) { bv = wv[w]; bi = wi[w]; }
      bidx[k] = bi;
      dist[bi] = 3.4e38f;
    }
    __syncthreads();
  }
  if (tid < KNN) neigh[(size_t)i * KNN + tid] = base + bidx[tid];
  // rel, bf16, K-padded to 32 with zeros
  for (int t = tid; t < KNN * 32; t += 256) {
    int k = t >> 5, c = t & 31;
    int j = bidx[k];
    unsigned short o = 0;
    if (c == 0) o = f2bf(xi - px[j]);
    else if (c == 1) o = f2bf(yi - py[j]);
    else if (c == 2) o = f2bf(zi - pz[j]);
    rel_b[((size_t)i * KNN + k) * 32 + c] = o;
  }
}

// ---------------- weight prep: fp32 [K][N] -> bf16 [N][Kpad] (transposed, zero-padded) ----------------
__global__ __launch_bounds__(256)
void transpose_w(const float* __restrict__ W, unsigned short* __restrict__ out,
                 int K, int N, int Kpad) {
  int n = blockIdx.x;
  for (int k = threadIdx.x; k < Kpad; k += 256)
    out[(size_t)n * Kpad + k] = (k < K) ? f2bf(W[(size_t)k * N + n]) : (unsigned short)0;
}

// ---------------- pos fp32 [N,3] -> bf16 [N,32] padded ----------------
__global__ __launch_bounds__(256)
void prep_pos(const float* __restrict__ pos, unsigned short* __restrict__ posb) {
  int idx = blockIdx.x * 256 + threadIdx.x;
  int m = idx >> 5, c = idx & 31;
  posb[idx] = (c < 3) ? f2bf(pos[(size_t)m * 3 + c]) : (unsigned short)0;
}

// ---------------- bf16 MFMA GEMM: C[M,N] = A[M,K](bf16) @ Bt[N,K](bf16)^T (+bias) ----------------
// 128x128 tile, BK=32, 4 waves in 2x2, each wave 4x4 grid of 16x16x32 MFMA.
// LDS rows padded to 40 ushorts (80 B: 16B-aligned b128, 2-way-conflict only).
#define APAD 40
__global__ __launch_bounds__(256)
void gemm_mfma(const unsigned short* __restrict__ A, const unsigned short* __restrict__ Bt,
               const float* __restrict__ bias, float* __restrict__ Cf,
               unsigned short* __restrict__ Cb, int M, int Nn, int Kk) {
  __shared__ unsigned short As[128 * APAD];
  __shared__ unsigned short Bs[128 * APAD];
  int tid = threadIdx.x;
  int wave = tid >> 6, lane = tid & 63;
  int quad = lane >> 4, l16 = lane & 15;
  int wm = (wave >> 1) * 64, wn = (wave & 1) * 64;
  int m0 = blockIdx.y * 128, n0 = blockIdx.x * 128;
  f32x4 acc[4][4] = {};
  int srow = tid >> 2;           // 0..63
  int scol = (tid & 3) * 8;      // 0,8,16,24
  for (int k0 = 0; k0 < Kk; k0 += 32) {
    #pragma unroll
    for (int h = 0; h < 2; ++h) {
      int r = srow + h * 64;
      int gm = m0 + r;
      uint4v va = {0, 0, 0, 0};
      if (gm < M) va = *(const uint4v*)(A + (size_t)gm * Kk + k0 + scol);
      *(uint4v*)(&As[r * APAD + scol]) = va;
      int gn = n0 + r;                      // N is always a multiple of 128
      uint4v vb = *(const uint4v*)(Bt + (size_t)gn * Kk + k0 + scol);
      *(uint4v*)(&Bs[r * APAD + scol]) = vb;
    }
    __syncthreads();
    bf16x8 af[4], bf[4];
    #pragma unroll
    for (int mi = 0; mi < 4; ++mi)
      af[mi] = __builtin_bit_cast(bf16x8, *(const uint4v*)(&As[(wm + mi * 16 + l16) * APAD + quad * 8]));
    #pragma unroll
    for (int ni = 0; ni < 4; ++ni)
      bf[ni] = __builtin_bit_cast(bf16x8, *(const uint4v*)(&Bs[(wn + ni * 16 + l16) * APAD + quad * 8]));
    #pragma unroll
    for (int mi = 0; mi < 4; ++mi)
      #pragma unroll
      for (int ni = 0; ni < 4; ++ni)
        acc[mi][ni] = __builtin_amdgcn_mfma_f32_16x16x32_bf16(af[mi], bf[ni], acc[mi][ni], 0, 0, 0);
    __syncthreads();
  }
  float bvs[4]; int gns[4];
  #pragma unroll
  for (int ni = 0; ni < 4; ++ni) {
    gns[ni] = n0 + wn + ni * 16 + l16;
    bvs[ni] = bias ? bias[gns[ni]] : 0.f;
  }
  #pragma unroll
  for (int mi = 0; mi < 4; ++mi) {
    #pragma unroll
    for (int r = 0; r < 4; ++r) {
      int gm = m0 + wm + mi * 16 + quad * 4 + r;
      if (gm >= M) continue;
      #pragma unroll
      for (int ni = 0; ni < 4; ++ni) {
        float val = acc[mi][ni][r] + bvs[ni];
        if (Cf) Cf[(size_t)gm * Nn + gns[ni]] = val;
        if (Cb) Cb[(size_t)gm * Nn + gns[ni]] = f2bf(val);
      }
    }
  }
}

// ---------------- fp32 tiled GEMM (head only, M=8) ----------------
#define BM 64
#define BN 64
#define BK 16
__global__ __launch_bounds__(256)
void gemm_bias(const float* __restrict__ A, const float* __restrict__ Bw,
               const float* __restrict__ bias, float* __restrict__ C,
               int M, int Nn, int Kk) {
  __shared__ float Asm[BK][BM + 1];
  __shared__ float Bsm[BK][BN + 1];
  int bm = blockIdx.y * BM, bn = blockIdx.x * BN;
  int tid = threadIdx.x;
  int tx = tid & 15, ty = tid >> 4;
  float acc[4][4] = {{0.f}};
  for (int k0 = 0; k0 < Kk; k0 += BK) {
    #pragma unroll
    for (int ii = 0; ii < 4; ++ii) {
      int e = tid + ii * 256;
      int m = e >> 4, k = e & 15;
      int gm = bm + m, gk = k0 + k;
      Asm[k][m] = (gm < M && gk < Kk) ? A[(size_t)gm * Kk + gk] : 0.f;
    }
    #pragma unroll
    for (int ii = 0; ii < 4; ++ii) {
      int e = tid + ii * 256;
      int k = e >> 6, n = e & 63;
      int gk = k0 + k, gn = bn + n;
      Bsm[k][n] = (gk < Kk && gn < Nn) ? Bw[(size_t)gk * Nn + gn] : 0.f;
    }
    __syncthreads();
    #pragma unroll
    for (int kk = 0; kk < BK; ++kk) {
      float a[4], b[4];
      #pragma unroll
      for (int ii = 0; ii < 4; ++ii) a[ii] = Asm[kk][ty * 4 + ii];
      #pragma unroll
      for (int jj = 0; jj < 4; ++jj) b[jj] = Bsm[kk][tx * 4 + jj];
      #pragma unroll
      for (int ii = 0; ii < 4; ++ii)
        #pragma unroll
        for (int jj = 0; jj < 4; ++jj)
          acc[ii][jj] += a[ii] * b[jj];
    }
    __syncthreads();
  }
  #pragma unroll
  for (int ii = 0; ii < 4; ++ii) {
    int gm = bm + ty * 4 + ii;
    if (gm >= M) continue;
    #pragma unroll
    for (int jj = 0; jj < 4; ++jj) {
      int gn = bn + tx * 4 + jj;
      if (gn >= Nn) continue;
      float vv = acc[ii][jj];
      if (bias) vv += bias[gn];
      C[(size_t)gm * Nn + gn] = vv;
    }
  }
}

// ---------------- LayerNorm + ELU; fp32 in, optional fp32 out + optional bf16 out ----------------
__global__ __launch_bounds__(256)
void ln_elu_kernel(const float* __restrict__ in, float* __restrict__ outf,
                   unsigned short* __restrict__ outb,
                   const float* __restrict__ g, const float* __restrict__ bb,
                   int Cn, int do_elu) {
  __shared__ float sdata[4];
  size_t row = blockIdx.x;
  const float* x = in + row * Cn;
  int tid = threadIdx.x;
  float v0 = x[tid];
  float v1 = (Cn == 512) ? x[tid + 256] : 0.f;
  float s = v0 + v1;
  #pragma unroll
  for (int off = 32; off > 0; off >>= 1) s += __shfl_xor(s, off, 64);
  if ((tid & 63) == 0) sdata[tid >> 6] = s;
  __syncthreads();
  float mean = (sdata[0] + sdata[1] + sdata[2] + sdata[3]) / (float)Cn;
  float d0 = v0 - mean;
  float d1 = (Cn == 512) ? (v1 - mean) : 0.f;
  float sq = d0 * d0 + d1 * d1;
  __syncthreads();
  #pragma unroll
  for (int off = 32; off > 0; off >>= 1) sq += __shfl_xor(sq, off, 64);
  if ((tid & 63) == 0) sdata[tid >> 6] = sq;
  __syncthreads();
  float var = (sdata[0] + sdata[1] + sdata[2] + sdata[3]) / (float)Cn;
  float r = rsqrtf(var + 1e-5f);
  float y0 = d0 * r * g[tid] + bb[tid];
  if (do_elu) y0 = (y0 > 0.f) ? y0 : (expf(y0) - 1.f);
  if (outf) outf[row * Cn + tid] = y0;
  if (outb) outb[row * Cn + tid] = f2bf(y0);
  if (Cn == 512) {
    float y1 = d1 * r * g[tid + 256] + bb[tid + 256];
    if (do_elu) y1 = (y1 > 0.f) ? y1 : (expf(y1) - 1.f);
    if (outf) outf[row * Cn + tid + 256] = y1;
    if (outb) outb[row * Cn + tid + 256] = f2bf(y1);
  }
}

// ---------------- attn-MLP input: t[e,c] = a_dst[i,c] - a_src[j,c] + delta[e,c] -> bf16 ----------------
__global__ __launch_bounds__(256)
void build_attn_in(const float* __restrict__ a_dst, const float* __restrict__ a_src,
                   const float* __restrict__ delta_f, const int* __restrict__ neigh,
                   unsigned short* __restrict__ t_b, int node0, int ec) {
  int e_local = blockIdx.x * 2 + (threadIdx.x >> 7);
  if (e_local >= ec) return;
  int c2 = (threadIdx.x & 127) * 2;
  int i = node0 + e_local / KNN;
  int j = neigh[(size_t)node0 * KNN + e_local];
  float2 d = *(const float2*)&a_dst[(size_t)i * HDIM + c2];
  float2 s = *(const float2*)&a_src[(size_t)j * HDIM + c2];
  float2 dl = *(const float2*)&delta_f[(size_t)e_local * HDIM + c2];
  unsigned o = (unsigned)f2bf(d.x - s.x + dl.x) | ((unsigned)f2bf(d.y - s.y + dl.y) << 16);
  *(unsigned*)&t_b[(size_t)e_local * HDIM + c2] = o;
}

// ---------------- per-channel softmax over K + weighted aggregation (fp32) ----------------
__global__ __launch_bounds__(256)
void softmax_agg(const float* __restrict__ alpha_f, const float* __restrict__ delta_f,
                 const float* __restrict__ v, const int* __restrict__ neigh,
                 float* __restrict__ agg, int node0) {
  int nl = blockIdx.x;
  int c = threadIdx.x;
  int i = node0 + nl;
  float av[KNN];
  float mx = -3.4e38f;
  #pragma unroll
  for (int k = 0; k < KNN; ++k) {
    av[k] = alpha_f[((size_t)nl * KNN + k) * HDIM + c];
    mx = fmaxf(mx, av[k]);
  }
  float ssum = 0.f;
  #pragma unroll
  for (int k = 0; k < KNN; ++k) { av[k] = expf(av[k] - mx); ssum += av[k]; }
  float inv = 1.f / ssum;
  float acc = 0.f;
  #pragma unroll
  for (int k = 0; k < KNN; ++k) {
    int j = neigh[(size_t)i * KNN + k];
    acc += av[k] * inv * (v[(size_t)j * HDIM + c] + delta_f[((size_t)nl * KNN + k) * HDIM + c]);
  }
  agg[(size_t)i * HDIM + c] = acc;
}

// ---------------- x += res_alpha[l] * h ; xb = bf16(x) ----------------
__global__ __launch_bounds__(256)
void axpy_res(float* __restrict__ x, unsigned short* __restrict__ xb,
              const float* __restrict__ h, const float* __restrict__ alpha, int l) {
  size_t idx = (size_t)blockIdx.x * 256 + threadIdx.x;
  float nv = x[idx] + alpha[l] * h[idx];
  x[idx] = nv;
  xb[idx] = f2bf(nv);
}

// ---------------- global max pool per cloud ----------------
__global__ __launch_bounds__(256)
void seg_max(const float* __restrict__ h, float* __restrict__ pooled) {
  int b = blockIdx.x;
  int c = threadIdx.x;
  float m = -3.4e38f;
  for (int p = 0; p < PPC; ++p)
    m = fmaxf(m, h[((size_t)(b * PPC + p)) * HDIM + c]);
  pooled[(size_t)b * HDIM + c] = m;
}

extern "C" void kernel_launch(void* const* d_in, const int* in_sizes, int n_in,
                              void* d_out, int out_size, void* d_ws, size_t ws_size,
                              hipStream_t stream) {
  const float* pos       = (const float*)d_in[0];
  const float* ffm_W     = (const float*)d_in[2];
  const float* ffm_b     = (const float*)d_in[3];
  const float* lin_W     = (const float*)d_in[4];
  const float* src_W     = (const float*)d_in[5];
  const float* dst_W     = (const float*)d_in[6];
  const float* pos1_W    = (const float*)d_in[7];
  const float* pos1_b    = (const float*)d_in[8];
  const float* pos_ln1_g = (const float*)d_in[9];
  const float* pos_ln1_b = (const float*)d_in[10];
  const float* pos2_W    = (const float*)d_in[11];
  const float* pos2_b    = (const float*)d_in[12];
  const float* pos_ln2_g = (const float*)d_in[13];
  const float* pos_ln2_b = (const float*)d_in[14];
  const float* att1_W    = (const float*)d_in[15];
  const float* att1_b    = (const float*)d_in[16];
  const float* att_ln1_g = (const float*)d_in[17];
  const float* att_ln1_b = (const float*)d_in[18];
  const float* att2_W    = (const float*)d_in[19];
  const float* att2_b    = (const float*)d_in[20];
  const float* att_ln2_g = (const float*)d_in[21];
  const float* att_ln2_b = (const float*)d_in[22];
  const float* blk_ln_g  = (const float*)d_in[23];
  const float* blk_ln_b  = (const float*)d_in[24];
  const float* blk_W     = (const float*)d_in[25];
  const float* blk_b     = (const float*)d_in[26];
  const float* res_alpha = (const float*)d_in[27];
  const float* r1_W = (const float*)d_in[28]; const float* r1_b = (const float*)d_in[29];
  const float* r2_W = (const float*)d_in[30]; const float* r2_b = (const float*)d_in[31];
  const float* r2_ln_g = (const float*)d_in[32]; const float* r2_ln_b = (const float*)d_in[33];
  const float* r3_W = (const float*)d_in[34]; const float* r3_b = (const float*)d_in[35];
  const float* r3_ln_g = (const float*)d_in[36]; const float* r3_ln_b = (const float*)d_in[37];
  const float* r4_W = (const float*)d_in[38]; const float* r4_b = (const float*)d_in[39];
  float* out = (float*)d_out;

  // ---- workspace carve-up (256B-aligned blocks) ----
  char* wsp = (char*)d_ws;
  auto alloc = [&](size_t bytes) -> void* {
    void* p = (void*)wsp;
    wsp += (bytes + 255) & ~(size_t)255;
    return p;
  };
  int*            neigh = (int*)alloc(EDG * sizeof(int));
  unsigned short* rel_b = (unsigned short*)alloc((size_t)EDG * 32 * 2);
  unsigned short* posb  = (unsigned short*)alloc((size_t)NPTS * 32 * 2);
  float* x     = (float*)alloc((size_t)NPTS * HDIM * 4);
  unsigned short* xb    = (unsigned short*)alloc((size_t)NPTS * HDIM * 2);
  unsigned short* xln_b = (unsigned short*)alloc((size_t)NPTS * HDIM * 2);
  float* a_src = (float*)alloc((size_t)NPTS * HDIM * 4);
  float* a_dst = (float*)alloc((size_t)NPTS * HDIM * 4);
  float* v     = (float*)alloc((size_t)NPTS * HDIM * 4);
  float* agg   = (float*)alloc((size_t)NPTS * HDIM * 4);
  float* pooled = (float*)alloc((size_t)BCL * HDIM * 4);
  float* hh     = (float*)alloc((size_t)BCL * HDIM * 4);
  // bf16 transposed weights
  unsigned short* ffmt = (unsigned short*)alloc((size_t)HDIM * 32 * 2);
  unsigned short* r1t  = (unsigned short*)alloc((size_t)HDIM * HDIM * 2);
  unsigned short *lint[NL], *srct[NL], *dstt[NL], *blkt[NL];
  unsigned short *pos1t[NL], *pos2t[NL], *att1t[NL], *att2t[NL];
  for (int l = 0; l < NL; ++l) {
    lint[l]  = (unsigned short*)alloc((size_t)HDIM * HDIM * 2);
    srct[l]  = (unsigned short*)alloc((size_t)HDIM * HDIM * 2);
    dstt[l]  = (unsigned short*)alloc((size_t)HDIM * HDIM * 2);
    blkt[l]  = (unsigned short*)alloc((size_t)HDIM * HDIM * 2);
    pos1t[l] = (unsigned short*)alloc((size_t)HD2 * 32 * 2);
    pos2t[l] = (unsigned short*)alloc((size_t)HDIM * HD2 * 2);
    att1t[l] = (unsigned short*)alloc((size_t)HD2 * HDIM * 2);
    att2t[l] = (unsigned short*)alloc((size_t)HDIM * HD2 * 2);
  }
  // chunked edge buffers
  size_t used = (size_t)(wsp - (char*)d_ws);
  size_t avail = (ws_size > used) ? (ws_size - used) : 0;
  size_t per_node = (size_t)KNN * (HD2 * 4 + HD2 * 2 + HDIM * 4 + HDIM * 2 + HDIM * 4) + 2048;
  int Nc = (int)(avail / per_node);
  if (Nc > NPTS) Nc = NPTS;
  Nc &= ~31;
  if (Nc < 32) Nc = 32;
  float*          hid_f   = (float*)alloc((size_t)Nc * KNN * HD2 * 4);
  unsigned short* hid_b   = (unsigned short*)alloc((size_t)Nc * KNN * HD2 * 2);
  float*          delta_f = (float*)alloc((size_t)Nc * KNN * HDIM * 4);
  unsigned short* t_b     = (unsigned short*)alloc((size_t)Nc * KNN * HDIM * 2);
  float*          alpha_f = (float*)alloc((size_t)Nc * KNN * HDIM * 4);

  auto mgemm = [&](const unsigned short* A, const unsigned short* Bt, const float* bias,
                   float* Cf, unsigned short* Cb, int M, int Nn, int Kk) {
    dim3 g(Nn / 128, (M + 127) / 128);
    gemm_mfma<<<g, dim3(256), 0, stream>>>(A, Bt, bias, Cf, Cb, M, Nn, Kk);
  };
  auto fgemm = [&](const float* A, const float* Bw, const float* bias, float* Cp,
                   int M, int Nn, int Kk) {
    dim3 g((Nn + BN - 1) / BN, (M + BM - 1) / BM);
    gemm_bias<<<g, dim3(256), 0, stream>>>(A, Bw, bias, Cp, M, Nn, Kk);
  };

  // ---- weight prep ----
  transpose_w<<<HDIM, 256, 0, stream>>>(ffm_W, ffmt, 3, HDIM, 32);
  transpose_w<<<HDIM, 256, 0, stream>>>(r1_W, r1t, HDIM, HDIM, HDIM);
  for (int l = 0; l < NL; ++l) {
    transpose_w<<<HDIM, 256, 0, stream>>>(lin_W + (size_t)l * HDIM * HDIM, lint[l], HDIM, HDIM, HDIM);
    transpose_w<<<HDIM, 256, 0, stream>>>(src_W + (size_t)l * HDIM * HDIM, srct[l], HDIM, HDIM, HDIM);
    transpose_w<<<HDIM, 256, 0, stream>>>(dst_W + (size_t)l * HDIM * HDIM, dstt[l], HDIM, HDIM, HDIM);
    transpose_w<<<HDIM, 256, 0, stream>>>(blk_W + (size_t)l * HDIM * HDIM, blkt[l], HDIM, HDIM, HDIM);
    transpose_w<<<HD2, 256, 0, stream>>>(pos1_W + (size_t)l * 3 * HD2, pos1t[l], 3, HD2, 32);
    transpose_w<<<HDIM, 256, 0, stream>>>(pos2_W + (size_t)l * HD2 * HDIM, pos2t[l], HD2, HDIM, HD2);
    transpose_w<<<HD2, 256, 0, stream>>>(att1_W + (size_t)l * HDIM * HD2, att1t[l], HDIM, HD2, HDIM);
    transpose_w<<<HDIM, 256, 0, stream>>>(att2_W + (size_t)l * HD2 * HDIM, att2t[l], HD2, HDIM, HD2);
  }

  // ---- graph + stem ----
  knn_block<<<NPTS, 256, 0, stream>>>(pos, neigh, rel_b);
  prep_pos<<<NPTS * 32 / 256, 256, 0, stream>>>(pos, posb);
  mgemm(posb, ffmt, ffm_b, x, xb, NPTS, HDIM, 32);

  // ---- transformer layers ----
  for (int l = 0; l < NL; ++l) {
    mgemm(xb, srct[l], nullptr, a_src, nullptr, NPTS, HDIM, HDIM);
    mgemm(xb, dstt[l], nullptr, a_dst, nullptr, NPTS, HDIM, HDIM);
    mgemm(xb, lint[l], nullptr, v,     nullptr, NPTS, HDIM, HDIM);

    for (int n0 = 0; n0 < NPTS; n0 += Nc) {
      int nc = (Nc < NPTS - n0) ? Nc : (NPTS - n0);
      int ec = nc * KNN;
      // pos_nn
      mgemm(rel_b + (size_t)n0 * KNN * 32, pos1t[l], pos1_b + (size_t)l * HD2,
            hid_f, nullptr, ec, HD2, 32);
      ln_elu_kernel<<<ec, 256, 0, stream>>>(hid_f, nullptr, hid_b,
                                            pos_ln1_g + (size_t)l * HD2, pos_ln1_b + (size_t)l * HD2, HD2, 1);
      mgemm(hid_b, pos2t[l], pos2_b + (size_t)l * HDIM, delta_f, nullptr, ec, HDIM, HD2);
      ln_elu_kernel<<<ec, 256, 0, stream>>>(delta_f, delta_f, nullptr,
                                            pos_ln2_g + (size_t)l * HDIM, pos_ln2_b + (size_t)l * HDIM, HDIM, 1);
      // attn_nn
      build_attn_in<<<ec / 2, 256, 0, stream>>>(a_dst, a_src, delta_f, neigh, t_b, n0, ec);
      mgemm(t_b, att1t[l], att1_b + (size_t)l * HD2, hid_f, nullptr, ec, HD2, HDIM);
      ln_elu_kernel<<<ec, 256, 0, stream>>>(hid_f, nullptr, hid_b,
                                            att_ln1_g + (size_t)l * HD2, att_ln1_b + (size_t)l * HD2, HD2, 1);
      mgemm(hid_b, att2t[l], att2_b + (size_t)l * HDIM, alpha_f, nullptr, ec, HDIM, HD2);
      ln_elu_kernel<<<ec, 256, 0, stream>>>(alpha_f, alpha_f, nullptr,
                                            att_ln2_g + (size_t)l * HDIM, att_ln2_b + (size_t)l * HDIM, HDIM, 1);
      softmax_agg<<<nc, 256, 0, stream>>>(alpha_f, delta_f, v, neigh, agg, n0);
    }
    // tail
    ln_elu_kernel<<<NPTS, 256, 0, stream>>>(agg, nullptr, xln_b,
                                            blk_ln_g + (size_t)l * HDIM, blk_ln_b + (size_t)l * HDIM, HDIM, 1);
    mgemm(xln_b, blkt[l], blk_b + (size_t)l * HDIM, a_dst, nullptr, NPTS, HDIM, HDIM);
    axpy_res<<<(NPTS * HDIM) / 256, 256, 0, stream>>>(x, xb, a_dst, res_alpha, l);
  }

  // ---- regression head ----
  mgemm(xb, r1t, r1_b, agg, nullptr, NPTS, HDIM, HDIM);
  seg_max<<<BCL, 256, 0, stream>>>(agg, pooled);
  fgemm(pooled, r2_W, r2_b, hh, BCL, HDIM, HDIM);
  ln_elu_kernel<<<BCL, 256, 0, stream>>>(hh, hh, nullptr, r2_ln_g, r2_ln_b, HDIM, 1);
  fgemm(hh, r3_W, r3_b, pooled, BCL, HDIM, HDIM);
  ln_elu_kernel<<<BCL, 256, 0, stream>>>(pooled, pooled, nullptr, r3_ln_g, r3_ln_b, HDIM, 1);
  fgemm(pooled, r4_W, r4_b, out, BCL, NCOMP, HDIM);
}

// Round 3
// 3068.048 us; speedup vs baseline: 6.7305x; 1.4663x over previous
//
#include <hip/hip_runtime.h>
#include <math.h>

#define NPTS 8192
#define PPC  1024
#define BCL  8
#define KNN  20
#define HDIM 256
#define HD2  512
#define NL   3
#define NCOMP 512
#define EDG  (NPTS*KNN)

typedef __bf16 bf16x8 __attribute__((ext_vector_type(8)));
typedef float f32x4 __attribute__((ext_vector_type(4)));
typedef unsigned int uint4v __attribute__((ext_vector_type(4)));

__device__ inline unsigned short f2bf(float f) {
  unsigned u = __float_as_uint(f);
  u += 0x7FFF + ((u >> 16) & 1);   // RNE
  return (unsigned short)(u >> 16);
}
__device__ inline float bf2f(unsigned short u) {
  return __uint_as_float((unsigned)u << 16);
}

// ---------------- KNN: one block per point, LDS distance array + 20x parallel argmin ----------------
__global__ __launch_bounds__(256)
void knn_block(const float* __restrict__ pos, int* __restrict__ neigh,
               unsigned short* __restrict__ rel_b) {
  __shared__ float px[PPC], py[PPC], pz[PPC];
  __shared__ float dist[PPC];
  __shared__ float wv[4]; __shared__ int wi[4];
  __shared__ int bidx[KNN];
  int i = blockIdx.x;
  int base = i & ~(PPC - 1);
  int tid = threadIdx.x;
  for (int t = tid; t < PPC; t += 256) {
    px[t] = pos[(size_t)(base + t) * 3 + 0];
    py[t] = pos[(size_t)(base + t) * 3 + 1];
    pz[t] = pos[(size_t)(base + t) * 3 + 2];
  }
  __syncthreads();
  float xi = px[i - base], yi = py[i - base], zi = pz[i - base];
  for (int t = tid; t < PPC; t += 256) {
    float dx = xi - px[t], dy = yi - py[t], dz = zi - pz[t];
    float d2 = dx * dx + dy * dy + dz * dz;
    dist[t] = (base + t == i) ? 3.4e38f : d2;
  }
  __syncthreads();
  int lane = tid & 63, wave = tid >> 6;
  for (int k = 0; k < KNN; ++k) {
    int id = tid * 4;
    float v = dist[id];
    #pragma unroll
    for (int q = 1; q < 4; ++q) {
      float d = dist[tid * 4 + q];
      if (d < v) { v = d; id = tid * 4 + q; }
    }
    #pragma unroll
    for (int off = 1; off < 64; off <<= 1) {
      float ov = __shfl_xor(v, off, 64);
      int oi = __shfl_xor(id, off, 64);
      if (ov < v || (ov == v && oi < id)) { v = ov; id = oi; }
    }
    if (lane == 0) { wv[wave] = v; wi[wave] = id; }
    __syncthreads();
    if (tid == 0) {
      float bv = wv[0]; int bi = wi[0];
      #pragma unroll
      for (int w = 1; w < 4; ++w)
        if (wv[w] < bv || (wv[w] == bv && wi[w] < bi)) { bv = wv[w]; bi = wi[w]; }
      bidx[k] = bi;
      dist[bi] = 3.4e38f;
    }
    __syncthreads();
  }
  if (tid < KNN) neigh[(size_t)i * KNN + tid] = base + bidx[tid];
  for (int t = tid; t < KNN * 32; t += 256) {
    int k = t >> 5, c = t & 31;
    int j = bidx[k];
    unsigned short o = 0;
    if (c == 0) o = f2bf(xi - px[j]);
    else if (c == 1) o = f2bf(yi - py[j]);
    else if (c == 2) o = f2bf(zi - pz[j]);
    rel_b[((size_t)i * KNN + k) * 32 + c] = o;
  }
}

// ---------------- weight prep: fp32 [K][N] -> bf16 [N][Kpad] ----------------
__global__ __launch_bounds__(256)
void transpose_w(const float* __restrict__ W, unsigned short* __restrict__ out,
                 int K, int N, int Kpad) {
  int n = blockIdx.x;
  for (int k = threadIdx.x; k < Kpad; k += 256)
    out[(size_t)n * Kpad + k] = (k < K) ? f2bf(W[(size_t)k * N + n]) : (unsigned short)0;
}

__global__ __launch_bounds__(256)
void prep_pos(const float* __restrict__ pos, unsigned short* __restrict__ posb) {
  int idx = blockIdx.x * 256 + threadIdx.x;
  int m = idx >> 5, c = idx & 31;
  posb[idx] = (c < 3) ? f2bf(pos[(size_t)m * 3 + c]) : (unsigned short)0;
}

// ================= fused GEMM + bias + LayerNorm + ELU -> bf16 =================
// Block tile BM x NN (full output width). 4 waves in 2(m) x 2(n).
// C layout per 16x16x32 MFMA: col = lane&15, row = (lane>>4)*4 + reg.
template<int BM, int NN, int KK>
__global__ __launch_bounds__(256)
void gemm_ln(const unsigned short* __restrict__ A, const unsigned short* __restrict__ Bt,
             const float* __restrict__ bias, const float* __restrict__ g,
             const float* __restrict__ be, unsigned short* __restrict__ outb) {
  constexpr int WMT = BM / 32;   // m-tiles per wave
  constexpr int WNT = NN / 32;   // n-tiles per wave
  __shared__ alignas(16) unsigned short As[BM * 40];
  __shared__ alignas(16) unsigned short Bs[NN * 40];
  __shared__ float lnsum[2][BM], lnsq[2][BM];
  int tid = threadIdx.x;
  int wave = tid >> 6, lane = tid & 63;
  int quad = lane >> 4, l16 = lane & 15;
  int wm = (wave >> 1) * (BM / 2), wni = wave & 1;
  int wn = wni * (NN / 2);
  int m0 = blockIdx.x * BM;
  f32x4 acc[WMT][WNT] = {};
  for (int k0 = 0; k0 < KK; k0 += 32) {
    for (int t = tid; t < BM * 4; t += 256) {
      int r = t >> 2, c = (t & 3) * 8;
      *(uint4v*)&As[r * 40 + c] = *(const uint4v*)(A + (size_t)(m0 + r) * KK + k0 + c);
    }
    for (int t = tid; t < NN * 4; t += 256) {
      int r = t >> 2, c = (t & 3) * 8;
      *(uint4v*)&Bs[r * 40 + c] = *(const uint4v*)(Bt + (size_t)r * KK + k0 + c);
    }
    __syncthreads();
    bf16x8 af[WMT], bfr[WNT];
    #pragma unroll
    for (int mi = 0; mi < WMT; ++mi)
      af[mi] = __builtin_bit_cast(bf16x8, *(const uint4v*)(&As[(wm + mi * 16 + l16) * 40 + quad * 8]));
    #pragma unroll
    for (int ni = 0; ni < WNT; ++ni)
      bfr[ni] = __builtin_bit_cast(bf16x8, *(const uint4v*)(&Bs[(wn + ni * 16 + l16) * 40 + quad * 8]));
    #pragma unroll
    for (int mi = 0; mi < WMT; ++mi)
      #pragma unroll
      for (int ni = 0; ni < WNT; ++ni)
        acc[mi][ni] = __builtin_amdgcn_mfma_f32_16x16x32_bf16(af[mi], bfr[ni], acc[mi][ni], 0, 0, 0);
    __syncthreads();
  }
  // bias + per-row partial sums (this wave covers cols [wn, wn+NN/2))
  float bvs[WNT], gvs[WNT], bevs[WNT];
  #pragma unroll
  for (int ni = 0; ni < WNT; ++ni) {
    int col = wn + ni * 16 + l16;
    bvs[ni] = bias[col]; gvs[ni] = g[col]; bevs[ni] = be[col];
  }
  #pragma unroll
  for (int mi = 0; mi < WMT; ++mi) {
    #pragma unroll
    for (int r = 0; r < 4; ++r) {
      float s = 0.f, sq = 0.f;
      #pragma unroll
      for (int ni = 0; ni < WNT; ++ni) {
        float val = acc[mi][ni][r] + bvs[ni];
        acc[mi][ni][r] = val;
        s += val; sq += val * val;
      }
      #pragma unroll
      for (int off = 1; off < 16; off <<= 1) {
        s  += __shfl_xor(s,  off, 64);
        sq += __shfl_xor(sq, off, 64);
      }
      int row = wm + mi * 16 + quad * 4 + r;
      if (l16 == 0) { lnsum[wni][row] = s; lnsq[wni][row] = sq; }
    }
  }
  __syncthreads();
  #pragma unroll
  for (int mi = 0; mi < WMT; ++mi) {
    #pragma unroll
    for (int r = 0; r < 4; ++r) {
      int row = wm + mi * 16 + quad * 4 + r;
      float tot = lnsum[0][row] + lnsum[1][row];
      float tsq = lnsq[0][row] + lnsq[1][row];
      float mean = tot / (float)NN;
      float var = tsq / (float)NN - mean * mean;
      float rr = rsqrtf(var + 1e-5f);
      size_t obase = (size_t)(m0 + row) * NN;
      #pragma unroll
      for (int ni = 0; ni < WNT; ++ni) {
        float y = (acc[mi][ni][r] - mean) * rr * gvs[ni] + bevs[ni];
        y = (y > 0.f) ? y : (expf(y) - 1.f);
        outb[obase + wn + ni * 16 + l16] = f2bf(y);
      }
    }
  }
}

// ---------------- plain bf16 MFMA GEMM (node GEMMs): optional fp32/bf16 out ----------------
#define APAD 40
__global__ __launch_bounds__(256)
void gemm_mfma(const unsigned short* __restrict__ A, const unsigned short* __restrict__ Bt,
               const float* __restrict__ bias, float* __restrict__ Cf,
               unsigned short* __restrict__ Cb, int M, int Nn, int Kk) {
  __shared__ alignas(16) unsigned short As[128 * APAD];
  __shared__ alignas(16) unsigned short Bs[128 * APAD];
  int tid = threadIdx.x;
  int wave = tid >> 6, lane = tid & 63;
  int quad = lane >> 4, l16 = lane & 15;
  int wm = (wave >> 1) * 64, wn = (wave & 1) * 64;
  int m0 = blockIdx.y * 128, n0 = blockIdx.x * 128;
  f32x4 acc[4][4] = {};
  int srow = tid >> 2;
  int scol = (tid & 3) * 8;
  for (int k0 = 0; k0 < Kk; k0 += 32) {
    #pragma unroll
    for (int h = 0; h < 2; ++h) {
      int r = srow + h * 64;
      int gm = m0 + r;
      uint4v va = {0, 0, 0, 0};
      if (gm < M) va = *(const uint4v*)(A + (size_t)gm * Kk + k0 + scol);
      *(uint4v*)(&As[r * APAD + scol]) = va;
      int gn = n0 + r;
      uint4v vb = *(const uint4v*)(Bt + (size_t)gn * Kk + k0 + scol);
      *(uint4v*)(&Bs[r * APAD + scol]) = vb;
    }
    __syncthreads();
    bf16x8 af[4], bfr[4];
    #pragma unroll
    for (int mi = 0; mi < 4; ++mi)
      af[mi] = __builtin_bit_cast(bf16x8, *(const uint4v*)(&As[(wm + mi * 16 + l16) * APAD + quad * 8]));
    #pragma unroll
    for (int ni = 0; ni < 4; ++ni)
      bfr[ni] = __builtin_bit_cast(bf16x8, *(const uint4v*)(&Bs[(wn + ni * 16 + l16) * APAD + quad * 8]));
    #pragma unroll
    for (int mi = 0; mi < 4; ++mi)
      #pragma unroll
      for (int ni = 0; ni < 4; ++ni)
        acc[mi][ni] = __builtin_amdgcn_mfma_f32_16x16x32_bf16(af[mi], bfr[ni], acc[mi][ni], 0, 0, 0);
    __syncthreads();
  }
  float bvs[4]; int gns[4];
  #pragma unroll
  for (int ni = 0; ni < 4; ++ni) {
    gns[ni] = n0 + wn + ni * 16 + l16;
    bvs[ni] = bias ? bias[gns[ni]] : 0.f;
  }
  #pragma unroll
  for (int mi = 0; mi < 4; ++mi) {
    #pragma unroll
    for (int r = 0; r < 4; ++r) {
      int gm = m0 + wm + mi * 16 + quad * 4 + r;
      if (gm >= M) continue;
      #pragma unroll
      for (int ni = 0; ni < 4; ++ni) {
        float val = acc[mi][ni][r] + bvs[ni];
        if (Cf) Cf[(size_t)gm * Nn + gns[ni]] = val;
        if (Cb) Cb[(size_t)gm * Nn + gns[ni]] = f2bf(val);
      }
    }
  }
}

// ---------------- fp32 tiled GEMM (head only, M=8) ----------------
#define BM0 64
#define BN0 64
#define BK0 16
__global__ __launch_bounds__(256)
void gemm_bias(const float* __restrict__ A, const float* __restrict__ Bw,
               const float* __restrict__ bias, float* __restrict__ C,
               int M, int Nn, int Kk) {
  __shared__ float Asm[BK0][BM0 + 1];
  __shared__ float Bsm[BK0][BN0 + 1];
  int bm = blockIdx.y * BM0, bn = blockIdx.x * BN0;
  int tid = threadIdx.x;
  int tx = tid & 15, ty = tid >> 4;
  float acc[4][4] = {{0.f}};
  for (int k0 = 0; k0 < Kk; k0 += BK0) {
    #pragma unroll
    for (int ii = 0; ii < 4; ++ii) {
      int e = tid + ii * 256;
      int m = e >> 4, k = e & 15;
      int gm = bm + m, gk = k0 + k;
      Asm[k][m] = (gm < M && gk < Kk) ? A[(size_t)gm * Kk + gk] : 0.f;
    }
    #pragma unroll
    for (int ii = 0; ii < 4; ++ii) {
      int e = tid + ii * 256;
      int k = e >> 6, n = e & 63;
      int gk = k0 + k, gn = bn + n;
      Bsm[k][n] = (gk < Kk && gn < Nn) ? Bw[(size_t)gk * Nn + gn] : 0.f;
    }
    __syncthreads();
    #pragma unroll
    for (int kk = 0; kk < BK0; ++kk) {
      float a[4], b[4];
      #pragma unroll
      for (int ii = 0; ii < 4; ++ii) a[ii] = Asm[kk][ty * 4 + ii];
      #pragma unroll
      for (int jj = 0; jj < 4; ++jj) b[jj] = Bsm[kk][tx * 4 + jj];
      #pragma unroll
      for (int ii = 0; ii < 4; ++ii)
        #pragma unroll
        for (int jj = 0; jj < 4; ++jj)
          acc[ii][jj] += a[ii] * b[jj];
    }
    __syncthreads();
  }
  #pragma unroll
  for (int ii = 0; ii < 4; ++ii) {
    int gm = bm + ty * 4 + ii;
    if (gm >= M) continue;
    #pragma unroll
    for (int jj = 0; jj < 4; ++jj) {
      int gn = bn + tx * 4 + jj;
      if (gn >= Nn) continue;
      float vv = acc[ii][jj];
      if (bias) vv += bias[gn];
      C[(size_t)gm * Nn + gn] = vv;
    }
  }
}

// ---------------- LayerNorm + ELU (node-side & head) ----------------
__global__ __launch_bounds__(256)
void ln_elu_kernel(const float* __restrict__ in, float* __restrict__ outf,
                   unsigned short* __restrict__ outb,
                   const float* __restrict__ g, const float* __restrict__ bb,
                   int Cn, int do_elu) {
  __shared__ float sdata[4];
  size_t row = blockIdx.x;
  const float* x = in + row * Cn;
  int tid = threadIdx.x;
  float v0 = x[tid];
  float v1 = (Cn == 512) ? x[tid + 256] : 0.f;
  float s = v0 + v1;
  #pragma unroll
  for (int off = 32; off > 0; off >>= 1) s += __shfl_xor(s, off, 64);
  if ((tid & 63) == 0) sdata[tid >> 6] = s;
  __syncthreads();
  float mean = (sdata[0] + sdata[1] + sdata[2] + sdata[3]) / (float)Cn;
  float d0 = v0 - mean;
  float d1 = (Cn == 512) ? (v1 - mean) : 0.f;
  float sq = d0 * d0 + d1 * d1;
  __syncthreads();
  #pragma unroll
  for (int off = 32; off > 0; off >>= 1) sq += __shfl_xor(sq, off, 64);
  if ((tid & 63) == 0) sdata[tid >> 6] = sq;
  __syncthreads();
  float var = (sdata[0] + sdata[1] + sdata[2] + sdata[3]) / (float)Cn;
  float r = rsqrtf(var + 1e-5f);
  float y0 = d0 * r * g[tid] + bb[tid];
  if (do_elu) y0 = (y0 > 0.f) ? y0 : (expf(y0) - 1.f);
  if (outf) outf[row * Cn + tid] = y0;
  if (outb) outb[row * Cn + tid] = f2bf(y0);
  if (Cn == 512) {
    float y1 = d1 * r * g[tid + 256] + bb[tid + 256];
    if (do_elu) y1 = (y1 > 0.f) ? y1 : (expf(y1) - 1.f);
    if (outf) outf[row * Cn + tid + 256] = y1;
    if (outb) outb[row * Cn + tid + 256] = f2bf(y1);
  }
}

// ---------------- t[e,c] = a_dst[i,c] - a_src[j,c] + delta[e,c] (all bf16) ----------------
__global__ __launch_bounds__(256)
void build_attn_in(const unsigned short* __restrict__ a_dst_b,
                   const unsigned short* __restrict__ a_src_b,
                   const unsigned short* __restrict__ delta_b,
                   const int* __restrict__ neigh,
                   unsigned short* __restrict__ t_b, int node0) {
  int e_local = blockIdx.x * 8 + (threadIdx.x >> 5);
  int c8 = (threadIdx.x & 31) * 8;
  int i = node0 + e_local / KNN;
  int j = neigh[(size_t)node0 * KNN + e_local];
  const unsigned short* pd = a_dst_b + (size_t)i * HDIM + c8;
  const unsigned short* ps = a_src_b + (size_t)j * HDIM + c8;
  const unsigned short* pl = delta_b + (size_t)e_local * HDIM + c8;
  unsigned short o[8];
  #pragma unroll
  for (int q = 0; q < 8; ++q)
    o[q] = f2bf(bf2f(pd[q]) - bf2f(ps[q]) + bf2f(pl[q]));
  *(uint4v*)(t_b + (size_t)e_local * HDIM + c8) = *(uint4v*)o;
}

// ---------------- per-channel softmax over K + weighted aggregation ----------------
__global__ __launch_bounds__(256)
void softmax_agg(const unsigned short* __restrict__ alpha_b,
                 const unsigned short* __restrict__ delta_b,
                 const unsigned short* __restrict__ v_b,
                 const int* __restrict__ neigh,
                 float* __restrict__ agg, int node0) {
  int nl = blockIdx.x;
  int c = threadIdx.x;
  int i = node0 + nl;
  float av[KNN];
  float mx = -3.4e38f;
  #pragma unroll
  for (int k = 0; k < KNN; ++k) {
    av[k] = bf2f(alpha_b[((size_t)nl * KNN + k) * HDIM + c]);
    mx = fmaxf(mx, av[k]);
  }
  float ssum = 0.f;
  #pragma unroll
  for (int k = 0; k < KNN; ++k) { av[k] = expf(av[k] - mx); ssum += av[k]; }
  float inv = 1.f / ssum;
  float acc = 0.f;
  #pragma unroll
  for (int k = 0; k < KNN; ++k) {
    int j = neigh[(size_t)i * KNN + k];
    acc += av[k] * inv * (bf2f(v_b[(size_t)j * HDIM + c]) +
                          bf2f(delta_b[((size_t)nl * KNN + k) * HDIM + c]));
  }
  agg[(size_t)i * HDIM + c] = acc;
}

// ---------------- x += res_alpha[l] * h ; xb = bf16(x) ----------------
__global__ __launch_bounds__(256)
void axpy_res(float* __restrict__ x, unsigned short* __restrict__ xb,
              const float* __restrict__ h, const float* __restrict__ alpha, int l) {
  size_t idx = (size_t)blockIdx.x * 256 + threadIdx.x;
  float nv = x[idx] + alpha[l] * h[idx];
  x[idx] = nv;
  xb[idx] = f2bf(nv);
}

// ---------------- global max pool, two-stage ----------------
__global__ __launch_bounds__(256)
void seg_max_p(const float* __restrict__ h, float* __restrict__ part) {
  int blk = blockIdx.x;           // 0..127
  int b = blk >> 4, ch = blk & 15;
  int c = threadIdx.x;
  const float* base = h + ((size_t)b * PPC + (size_t)ch * 64) * HDIM;
  float m = -3.4e38f;
  for (int p = 0; p < 64; ++p)
    m = fmaxf(m, base[(size_t)p * HDIM + c]);
  part[(size_t)blk * HDIM + c] = m;
}
__global__ __launch_bounds__(256)
void seg_max_f(const float* __restrict__ part, float* __restrict__ pooled) {
  int b = blockIdx.x;
  int c = threadIdx.x;
  float m = -3.4e38f;
  for (int k = 0; k < 16; ++k)
    m = fmaxf(m, part[(size_t)(b * 16 + k) * HDIM + c]);
  pooled[(size_t)b * HDIM + c] = m;
}

extern "C" void kernel_launch(void* const* d_in, const int* in_sizes, int n_in,
                              void* d_out, int out_size, void* d_ws, size_t ws_size,
                              hipStream_t stream) {
  const float* pos       = (const float*)d_in[0];
  const float* ffm_W     = (const float*)d_in[2];
  const float* ffm_b     = (const float*)d_in[3];
  const float* lin_W     = (const float*)d_in[4];
  const float* src_W     = (const float*)d_in[5];
  const float* dst_W     = (const float*)d_in[6];
  const float* pos1_W    = (const float*)d_in[7];
  const float* pos1_b    = (const float*)d_in[8];
  const float* pos_ln1_g = (const float*)d_in[9];
  const float* pos_ln1_b = (const float*)d_in[10];
  const float* pos2_W    = (const float*)d_in[11];
  const float* pos2_b    = (const float*)d_in[12];
  const float* pos_ln2_g = (const float*)d_in[13];
  const float* pos_ln2_b = (const float*)d_in[14];
  const float* att1_W    = (const float*)d_in[15];
  const float* att1_b    = (const float*)d_in[16];
  const float* att_ln1_g = (const float*)d_in[17];
  const float* att_ln1_b = (const float*)d_in[18];
  const float* att2_W    = (const float*)d_in[19];
  const float* att2_b    = (const float*)d_in[20];
  const float* att_ln2_g = (const float*)d_in[21];
  const float* att_ln2_b = (const float*)d_in[22];
  const float* blk_ln_g  = (const float*)d_in[23];
  const float* blk_ln_b  = (const float*)d_in[24];
  const float* blk_W     = (const float*)d_in[25];
  const float* blk_b     = (const float*)d_in[26];
  const float* res_alpha = (const float*)d_in[27];
  const float* r1_W = (const float*)d_in[28]; const float* r1_b = (const float*)d_in[29];
  const float* r2_W = (const float*)d_in[30]; const float* r2_b = (const float*)d_in[31];
  const float* r2_ln_g = (const float*)d_in[32]; const float* r2_ln_b = (const float*)d_in[33];
  const float* r3_W = (const float*)d_in[34]; const float* r3_b = (const float*)d_in[35];
  const float* r3_ln_g = (const float*)d_in[36]; const float* r3_ln_b = (const float*)d_in[37];
  const float* r4_W = (const float*)d_in[38]; const float* r4_b = (const float*)d_in[39];
  float* out = (float*)d_out;

  // ---- workspace carve-up ----
  char* wsp = (char*)d_ws;
  auto alloc = [&](size_t bytes) -> void* {
    void* p = (void*)wsp;
    wsp += (bytes + 255) & ~(size_t)255;
    return p;
  };
  int*            neigh   = (int*)alloc(EDG * sizeof(int));
  unsigned short* rel_b   = (unsigned short*)alloc((size_t)EDG * 32 * 2);
  unsigned short* posb    = (unsigned short*)alloc((size_t)NPTS * 32 * 2);
  float*          x       = (float*)alloc((size_t)NPTS * HDIM * 4);
  unsigned short* xb      = (unsigned short*)alloc((size_t)NPTS * HDIM * 2);
  unsigned short* xln_b   = (unsigned short*)alloc((size_t)NPTS * HDIM * 2);
  unsigned short* a_src_b = (unsigned short*)alloc((size_t)NPTS * HDIM * 2);
  unsigned short* a_dst_b = (unsigned short*)alloc((size_t)NPTS * HDIM * 2);
  unsigned short* v_b     = (unsigned short*)alloc((size_t)NPTS * HDIM * 2);
  float*          agg     = (float*)alloc((size_t)NPTS * HDIM * 4);
  float*          segp    = (float*)alloc((size_t)128 * HDIM * 4);
  float*          pooled  = (float*)alloc((size_t)BCL * HDIM * 4);
  float*          hh      = (float*)alloc((size_t)BCL * HDIM * 4);
  unsigned short* ffmt = (unsigned short*)alloc((size_t)HDIM * 32 * 2);
  unsigned short* r1t  = (unsigned short*)alloc((size_t)HDIM * HDIM * 2);
  unsigned short *lint[NL], *srct[NL], *dstt[NL], *blkt[NL];
  unsigned short *pos1t[NL], *pos2t[NL], *att1t[NL], *att2t[NL];
  for (int l = 0; l < NL; ++l) {
    lint[l]  = (unsigned short*)alloc((size_t)HDIM * HDIM * 2);
    srct[l]  = (unsigned short*)alloc((size_t)HDIM * HDIM * 2);
    dstt[l]  = (unsigned short*)alloc((size_t)HDIM * HDIM * 2);
    blkt[l]  = (unsigned short*)alloc((size_t)HDIM * HDIM * 2);
    pos1t[l] = (unsigned short*)alloc((size_t)HD2 * 32 * 2);
    pos2t[l] = (unsigned short*)alloc((size_t)HDIM * HD2 * 2);
    att1t[l] = (unsigned short*)alloc((size_t)HD2 * HDIM * 2);
    att2t[l] = (unsigned short*)alloc((size_t)HDIM * HD2 * 2);
  }
  // chunked edge buffers (all bf16 now)
  size_t used = (size_t)(wsp - (char*)d_ws);
  size_t avail = (ws_size > used) ? (ws_size - used) : 0;
  size_t per_node = (size_t)KNN * (HD2 * 2 + HDIM * 2 * 3) + 2048;
  int Nc = (int)(avail / per_node);
  if (Nc > NPTS) Nc = NPTS;
  Nc &= ~15;                // ec = Nc*20 divisible by 64
  if (Nc < 16) Nc = 16;
  unsigned short* hid_b   = (unsigned short*)alloc((size_t)Nc * KNN * HD2 * 2);
  unsigned short* delta_b = (unsigned short*)alloc((size_t)Nc * KNN * HDIM * 2);
  unsigned short* t_b     = (unsigned short*)alloc((size_t)Nc * KNN * HDIM * 2);
  unsigned short* alpha_b = (unsigned short*)alloc((size_t)Nc * KNN * HDIM * 2);

  auto mgemm = [&](const unsigned short* A, const unsigned short* Bt, const float* bias,
                   float* Cf, unsigned short* Cb, int M, int Nn, int Kk) {
    dim3 g(Nn / 128, (M + 127) / 128);
    gemm_mfma<<<g, dim3(256), 0, stream>>>(A, Bt, bias, Cf, Cb, M, Nn, Kk);
  };
  auto fgemm = [&](const float* A, const float* Bw, const float* bias, float* Cp,
                   int M, int Nn, int Kk) {
    dim3 g((Nn + BN0 - 1) / BN0, (M + BM0 - 1) / BM0);
    gemm_bias<<<g, dim3(256), 0, stream>>>(A, Bw, bias, Cp, M, Nn, Kk);
  };

  // ---- weight prep ----
  transpose_w<<<HDIM, 256, 0, stream>>>(ffm_W, ffmt, 3, HDIM, 32);
  transpose_w<<<HDIM, 256, 0, stream>>>(r1_W, r1t, HDIM, HDIM, HDIM);
  for (int l = 0; l < NL; ++l) {
    transpose_w<<<HDIM, 256, 0, stream>>>(lin_W + (size_t)l * HDIM * HDIM, lint[l], HDIM, HDIM, HDIM);
    transpose_w<<<HDIM, 256, 0, stream>>>(src_W + (size_t)l * HDIM * HDIM, srct[l], HDIM, HDIM, HDIM);
    transpose_w<<<HDIM, 256, 0, stream>>>(dst_W + (size_t)l * HDIM * HDIM, dstt[l], HDIM, HDIM, HDIM);
    transpose_w<<<HDIM, 256, 0, stream>>>(blk_W + (size_t)l * HDIM * HDIM, blkt[l], HDIM, HDIM, HDIM);
    transpose_w<<<HD2, 256, 0, stream>>>(pos1_W + (size_t)l * 3 * HD2, pos1t[l], 3, HD2, 32);
    transpose_w<<<HDIM, 256, 0, stream>>>(pos2_W + (size_t)l * HD2 * HDIM, pos2t[l], HD2, HDIM, HD2);
    transpose_w<<<HD2, 256, 0, stream>>>(att1_W + (size_t)l * HDIM * HD2, att1t[l], HDIM, HD2, HDIM);
    transpose_w<<<HDIM, 256, 0, stream>>>(att2_W + (size_t)l * HD2 * HDIM, att2t[l], HD2, HDIM, HD2);
  }

  // ---- graph + stem ----
  knn_block<<<NPTS, 256, 0, stream>>>(pos, neigh, rel_b);
  prep_pos<<<NPTS * 32 / 256, 256, 0, stream>>>(pos, posb);
  mgemm(posb, ffmt, ffm_b, x, xb, NPTS, HDIM, 32);

  // ---- transformer layers ----
  for (int l = 0; l < NL; ++l) {
    mgemm(xb, srct[l], nullptr, nullptr, a_src_b, NPTS, HDIM, HDIM);
    mgemm(xb, dstt[l], nullptr, nullptr, a_dst_b, NPTS, HDIM, HDIM);
    mgemm(xb, lint[l], nullptr, nullptr, v_b,     NPTS, HDIM, HDIM);

    for (int n0 = 0; n0 < NPTS; n0 += Nc) {
      int nc = (Nc < NPTS - n0) ? Nc : (NPTS - n0);
      int ec = nc * KNN;
      // pos_nn (fused LN+ELU epilogues)
      gemm_ln<32, 512, 32><<<ec / 32, 256, 0, stream>>>(
          rel_b + (size_t)n0 * KNN * 32, pos1t[l], pos1_b + (size_t)l * HD2,
          pos_ln1_g + (size_t)l * HD2, pos_ln1_b + (size_t)l * HD2, hid_b);
      gemm_ln<64, 256, 512><<<ec / 64, 256, 0, stream>>>(
          hid_b, pos2t[l], pos2_b + (size_t)l * HDIM,
          pos_ln2_g + (size_t)l * HDIM, pos_ln2_b + (size_t)l * HDIM, delta_b);
      // attn_nn
      build_attn_in<<<ec / 8, 256, 0, stream>>>(a_dst_b, a_src_b, delta_b, neigh, t_b, n0);
      gemm_ln<32, 512, 256><<<ec / 32, 256, 0, stream>>>(
          t_b, att1t[l], att1_b + (size_t)l * HD2,
          att_ln1_g + (size_t)l * HD2, att_ln1_b + (size_t)l * HD2, hid_b);
      gemm_ln<64, 256, 512><<<ec / 64, 256, 0, stream>>>(
          hid_b, att2t[l], att2_b + (size_t)l * HDIM,
          att_ln2_g + (size_t)l * HDIM, att_ln2_b + (size_t)l * HDIM, alpha_b);
      softmax_agg<<<nc, 256, 0, stream>>>(alpha_b, delta_b, v_b, neigh, agg, n0);
    }
    // tail: elu(LN(agg)) @ blk_W + b, residual
    ln_elu_kernel<<<NPTS, 256, 0, stream>>>(agg, nullptr, xln_b,
                                            blk_ln_g + (size_t)l * HDIM, blk_ln_b + (size_t)l * HDIM, HDIM, 1);
    mgemm(xln_b, blkt[l], blk_b + (size_t)l * HDIM, agg, nullptr, NPTS, HDIM, HDIM);
    axpy_res<<<(NPTS * HDIM) / 256, 256, 0, stream>>>(x, xb, agg, res_alpha, l);
  }

  // ---- regression head ----
  mgemm(xb, r1t, r1_b, agg, nullptr, NPTS, HDIM, HDIM);
  seg_max_p<<<128, 256, 0, stream>>>(agg, segp);
  seg_max_f<<<BCL, 256, 0, stream>>>(segp, pooled);
  fgemm(pooled, r2_W, r2_b, hh, BCL, HDIM, HDIM);
  ln_elu_kernel<<<BCL, 256, 0, stream>>>(hh, hh, nullptr, r2_ln_g, r2_ln_b, HDIM, 1);
  fgemm(hh, r3_W, r3_b, pooled, BCL, HDIM, HDIM);
  ln_elu_kernel<<<BCL, 256, 0, stream>>>(pooled, pooled, nullptr, r3_ln_g, r3_ln_b, HDIM, 1);
  fgemm(pooled, r4_W, r4_b, out, BCL, NCOMP, HDIM);
}

// Round 4
// 2733.121 us; speedup vs baseline: 7.5553x; 1.1225x over previous
//
#include <hip/hip_runtime.h>
#include <math.h>

#define NPTS 8192
#define PPC  1024
#define BCL  8
#define KNN  20
#define HDIM 256
#define HD2  512
#define NL   3
#define NCOMP 512
#define EDG  (NPTS*KNN)

typedef __bf16 bf16x8 __attribute__((ext_vector_type(8)));
typedef float f32x4 __attribute__((ext_vector_type(4)));
typedef unsigned int uint4v __attribute__((ext_vector_type(4)));
typedef unsigned short us8 __attribute__((ext_vector_type(8)));

__device__ inline unsigned short f2bf(float f) {
  unsigned u = __float_as_uint(f);
  u += 0x7FFF + ((u >> 16) & 1);   // RNE
  return (unsigned short)(u >> 16);
}
__device__ inline float bf2f(unsigned short u) {
  return __uint_as_float((unsigned)u << 16);
}
__device__ inline float elu(float y) { return (y > 0.f) ? y : (expf(y) - 1.f); }

// ---------------- KNN: one WAVE per point, register distances, no barriers in rounds ----------------
__global__ __launch_bounds__(256)
void knn_wave(const float* __restrict__ pos, int* __restrict__ neigh,
              float* __restrict__ rel_f) {
  __shared__ float px[PPC], py[PPC], pz[PPC];
  int tid = threadIdx.x;
  int i0 = blockIdx.x * 4;                    // 4 points per block, same cloud
  int base = i0 & ~(PPC - 1);
  for (int t = tid; t < PPC; t += 256) {
    px[t] = pos[(size_t)(base + t) * 3 + 0];
    py[t] = pos[(size_t)(base + t) * 3 + 1];
    pz[t] = pos[(size_t)(base + t) * 3 + 2];
  }
  __syncthreads();
  int wave = tid >> 6, lane = tid & 63;
  int i = i0 + wave;
  int il = i - base;
  float xi = px[il], yi = py[il], zi = pz[il];
  float d[16];
  #pragma unroll
  for (int q = 0; q < 16; ++q) {
    int t = lane + 64 * q;                    // candidate index within cloud
    float dx = xi - px[t], dy = yi - py[t], dz = zi - pz[t];
    float dd = dx * dx + dy * dy + dz * dz;
    d[q] = (t == il) ? 3.4e38f : dd;
  }
  int mywin = 0;
  for (int k = 0; k < KNN; ++k) {
    // lane-local argmin; idx == global candidate index (q*64+lane), ascending q => lowest idx on ties
    float v = d[0]; int idx = lane;
    #pragma unroll
    for (int q = 1; q < 16; ++q)
      if (d[q] < v) { v = d[q]; idx = q * 64 + lane; }
    #pragma unroll
    for (int off = 1; off < 64; off <<= 1) {
      float ov = __shfl_xor(v, off, 64);
      int oi = __shfl_xor(idx, off, 64);
      if (ov < v || (ov == v && oi < idx)) { v = ov; idx = oi; }
    }
    if (lane == k) mywin = idx;               // k < 20 < 64
    int qwin = idx >> 6;
    bool own = (idx & 63) == lane;
    #pragma unroll
    for (int q = 0; q < 16; ++q)
      if (own && q == qwin) d[q] = 3.4e38f;
  }
  if (lane < KNN) {
    neigh[(size_t)i * KNN + lane] = base + mywin;
    size_t rb = ((size_t)i * KNN + lane) * 3;
    rel_f[rb + 0] = xi - px[mywin];
    rel_f[rb + 1] = yi - py[mywin];
    rel_f[rb + 2] = zi - pz[mywin];
  }
}

// ---------------- weight prep: fp32 [K][N] -> bf16 [N][Kpad] ----------------
__global__ __launch_bounds__(256)
void transpose_w(const float* __restrict__ W, unsigned short* __restrict__ out,
                 int K, int N, int Kpad) {
  int n = blockIdx.x;
  for (int k = threadIdx.x; k < Kpad; k += 256)
    out[(size_t)n * Kpad + k] = (k < K) ? f2bf(W[(size_t)k * N + n]) : (unsigned short)0;
}

__global__ __launch_bounds__(256)
void prep_pos(const float* __restrict__ pos, unsigned short* __restrict__ posb) {
  int idx = blockIdx.x * 256 + threadIdx.x;
  int m = idx >> 5, c = idx & 31;
  posb[idx] = (c < 3) ? f2bf(pos[(size_t)m * 3 + c]) : (unsigned short)0;
}

// ================= pos_nn fused: [32 edges] rel(3) -> 512 (VALU) -> LN+ELU -> @pos2 -> LN+ELU -> delta =================
// smem: H[32][520]bf16 @0 (33280) | P2 region @33280 (20480): phase1 w1s/b1s/g1s/be1s, phase2 B2s[256][40]
//       LN @53760 (512) | relS @54272 (384)
__global__ __launch_bounds__(256)
void pos_fused(const float* __restrict__ rel_f, const float* __restrict__ W1,
               const float* __restrict__ b1, const float* __restrict__ g1,
               const float* __restrict__ be1,
               const unsigned short* __restrict__ B2t, const float* __restrict__ bias2,
               const float* __restrict__ g2, const float* __restrict__ be2,
               unsigned short* __restrict__ delta_b, int edge_base) {
  __shared__ alignas(16) char smem[54656];
  unsigned short* H = (unsigned short*)smem;                  // [32][520]
  float* w1s = (float*)(smem + 33280);                        // [3][512]
  float* b1s = w1s + 1536;
  float* g1s = b1s + 512;
  float* be1s = g1s + 512;
  unsigned short* B2s = (unsigned short*)(smem + 33280);      // [256][40] (phase2 overlay)
  float* lnsum = (float*)(smem + 53760);                      // [2][32]
  float* lnsq = lnsum + 64;
  float* relS = (float*)(smem + 54272);                       // [32][3]
  int tid = threadIdx.x;
  int wave = tid >> 6, lane = tid & 63;
  int el0 = blockIdx.x * 32;
  int eg0 = edge_base + el0;
  for (int t = tid; t < 1536; t += 256) w1s[t] = W1[t];
  for (int t = tid; t < 512; t += 256) { b1s[t] = b1[t]; g1s[t] = g1[t]; be1s[t] = be1[t]; }
  if (tid < 96) relS[tid] = rel_f[(size_t)eg0 * 3 + tid];
  __syncthreads();
  // ---- phase 1: rank-3 VALU, fp32; one row handled by 8 consecutive lanes ----
  {
    int rIW = lane >> 3, sub = lane & 7;
    int row = wave * 8 + rIW;
    float r0 = relS[row * 3 + 0], r1v = relS[row * 3 + 1], r2v = relS[row * 3 + 2];
    int cb = sub * 64;
    float h[64]; float s = 0.f, sq = 0.f;
    #pragma unroll
    for (int cc = 0; cc < 16; ++cc) {
      f32x4 w0 = *(const f32x4*)&w1s[cb + cc * 4];
      f32x4 wa = *(const f32x4*)&w1s[512 + cb + cc * 4];
      f32x4 wb = *(const f32x4*)&w1s[1024 + cb + cc * 4];
      f32x4 bb = *(const f32x4*)&b1s[cb + cc * 4];
      #pragma unroll
      for (int q = 0; q < 4; ++q) {
        float hv = fmaf(r0, w0[q], fmaf(r1v, wa[q], fmaf(r2v, wb[q], bb[q])));
        h[cc * 4 + q] = hv; s += hv; sq += hv * hv;
      }
    }
    #pragma unroll
    for (int off = 1; off < 8; off <<= 1) { s += __shfl_xor(s, off, 64); sq += __shfl_xor(sq, off, 64); }
    float mean = s * (1.f / 512.f);
    float var = sq * (1.f / 512.f) - mean * mean;
    float rr = rsqrtf(var + 1e-5f);
    #pragma unroll
    for (int cc = 0; cc < 8; ++cc) {
      f32x4 ga = *(const f32x4*)&g1s[cb + cc * 8];
      f32x4 gb = *(const f32x4*)&g1s[cb + cc * 8 + 4];
      f32x4 ba = *(const f32x4*)&be1s[cb + cc * 8];
      f32x4 bb2 = *(const f32x4*)&be1s[cb + cc * 8 + 4];
      unsigned short o[8];
      #pragma unroll
      for (int q = 0; q < 4; ++q) {
        o[q]     = f2bf(elu((h[cc * 8 + q]     - mean) * rr * ga[q] + ba[q]));
        o[q + 4] = f2bf(elu((h[cc * 8 + 4 + q] - mean) * rr * gb[q] + bb2[q]));
      }
      *(uint4v*)&H[row * 520 + cb + cc * 8] = *(uint4v*)o;
    }
  }
  __syncthreads();
  // ---- phase 2: MFMA H[32x512] @ B2t[256][512]^T -> 32x256, LN+ELU -> delta ----
  int quad = lane >> 4, l16 = lane & 15;
  int wm2 = (wave >> 1) * 16, wn2 = (wave & 1) * 128, wni = wave & 1;
  f32x4 acc2[8] = {};
  for (int k0 = 0; k0 < 512; k0 += 32) {
    for (int t = tid; t < 1024; t += 256) {
      int n = t >> 2, c = (t & 3) * 8;
      *(uint4v*)&B2s[n * 40 + c] = *(const uint4v*)(B2t + (size_t)n * 512 + k0 + c);
    }
    __syncthreads();
    bf16x8 a2 = __builtin_bit_cast(bf16x8, *(const uint4v*)&H[(wm2 + l16) * 520 + k0 + quad * 8]);
    #pragma unroll
    for (int ni = 0; ni < 8; ++ni) {
      bf16x8 b2v = __builtin_bit_cast(bf16x8, *(const uint4v*)&B2s[(wn2 + ni * 16 + l16) * 40 + quad * 8]);
      acc2[ni] = __builtin_amdgcn_mfma_f32_16x16x32_bf16(a2, b2v, acc2[ni], 0, 0, 0);
    }
    __syncthreads();
  }
  float bv[8], gv[8], bev[8];
  #pragma unroll
  for (int ni = 0; ni < 8; ++ni) {
    int col = wn2 + ni * 16 + l16;
    bv[ni] = bias2[col]; gv[ni] = g2[col]; bev[ni] = be2[col];
  }
  #pragma unroll
  for (int r = 0; r < 4; ++r) {
    int row = wm2 + quad * 4 + r;
    float s2 = 0.f, q2 = 0.f;
    #pragma unroll
    for (int ni = 0; ni < 8; ++ni) {
      float val = acc2[ni][r] + bv[ni];
      acc2[ni][r] = val; s2 += val; q2 += val * val;
    }
    #pragma unroll
    for (int off = 1; off < 16; off <<= 1) { s2 += __shfl_xor(s2, off, 64); q2 += __shfl_xor(q2, off, 64); }
    if (l16 == 0) { lnsum[wni * 32 + row] = s2; lnsq[wni * 32 + row] = q2; }
  }
  __syncthreads();
  #pragma unroll
  for (int r = 0; r < 4; ++r) {
    int row = wm2 + quad * 4 + r;
    float tot = lnsum[row] + lnsum[32 + row];
    float tsq = lnsq[row] + lnsq[32 + row];
    float mean = tot * (1.f / 256.f);
    float var = tsq * (1.f / 256.f) - mean * mean;
    float rr = rsqrtf(var + 1e-5f);
    size_t ob = (size_t)(el0 + row) * 256;
    #pragma unroll
    for (int ni = 0; ni < 8; ++ni)
      delta_b[ob + wn2 + ni * 16 + l16] = f2bf(elu((acc2[ni][r] - mean) * rr * gv[ni] + bev[ni]));
  }
}

// ================= attn fused: t built in staging -> @att1 -> LN+ELU (H in LDS) -> @att2 -> LN+ELU -> alpha =================
// smem: B1s[512][40]/B2s @0 (40960) | H[32][520] @40960 (33280) | LN @74240 (512) | iS/jS @74752 (256) | As[32][40] @75008 (2560)
__global__ __launch_bounds__(256)
void attn_fused(const unsigned short* __restrict__ a_dst_b,
                const unsigned short* __restrict__ a_src_b,
                const unsigned short* __restrict__ delta_b,
                const int* __restrict__ neigh,
                const unsigned short* __restrict__ B1t, const float* __restrict__ bias1,
                const float* __restrict__ g1, const float* __restrict__ be1,
                const unsigned short* __restrict__ B2t, const float* __restrict__ bias2,
                const float* __restrict__ g2, const float* __restrict__ be2,
                unsigned short* __restrict__ alpha_b, int edge_base) {
  __shared__ alignas(16) char smem[77568];
  unsigned short* B1s = (unsigned short*)smem;                 // [512][40] (B2s overlays)
  unsigned short* H   = (unsigned short*)(smem + 40960);       // [32][520]
  float* lnsum = (float*)(smem + 74240);
  float* lnsq  = lnsum + 64;
  int* iS = (int*)(smem + 74752);
  int* jS = iS + 32;
  unsigned short* As = (unsigned short*)(smem + 75008);        // [32][40]
  int tid = threadIdx.x;
  int wave = tid >> 6, lane = tid & 63;
  int quad = lane >> 4, l16 = lane & 15;
  int el0 = blockIdx.x * 32;
  int eg0 = edge_base + el0;
  if (tid < 32) { iS[tid] = (eg0 + tid) / KNN; jS[tid] = neigh[eg0 + tid]; }
  __syncthreads();
  // ---- phase 1: GEMM1 K=256, gathered A ----
  int wm1 = (wave >> 1) * 16, wn1 = (wave & 1) * 256, wni = wave & 1;
  f32x4 acc1[16] = {};
  for (int k0 = 0; k0 < 256; k0 += 32) {
    for (int t = tid; t < 2048; t += 256) {
      int n = t >> 2, c = (t & 3) * 8;
      *(uint4v*)&B1s[n * 40 + c] = *(const uint4v*)(B1t + (size_t)n * 256 + k0 + c);
    }
    if (tid < 128) {
      int r = tid >> 2, c = (tid & 3) * 8;
      int i = iS[r], j = jS[r], e = el0 + r;
      us8 pd = *(const us8*)(a_dst_b + (size_t)i * 256 + k0 + c);
      us8 ps = *(const us8*)(a_src_b + (size_t)j * 256 + k0 + c);
      us8 pl = *(const us8*)(delta_b + (size_t)e * 256 + k0 + c);
      unsigned short o[8];
      #pragma unroll
      for (int q = 0; q < 8; ++q)
        o[q] = f2bf(bf2f(pd[q]) - bf2f(ps[q]) + bf2f(pl[q]));
      *(uint4v*)&As[r * 40 + c] = *(uint4v*)o;
    }
    __syncthreads();
    bf16x8 a1 = __builtin_bit_cast(bf16x8, *(const uint4v*)&As[(wm1 + l16) * 40 + quad * 8]);
    #pragma unroll
    for (int ni = 0; ni < 16; ++ni) {
      bf16x8 b1v = __builtin_bit_cast(bf16x8, *(const uint4v*)&B1s[(wn1 + ni * 16 + l16) * 40 + quad * 8]);
      acc1[ni] = __builtin_amdgcn_mfma_f32_16x16x32_bf16(a1, b1v, acc1[ni], 0, 0, 0);
    }
    __syncthreads();
  }
  // epilogue 1: bias + LN(512) + ELU -> H (bf16)
  {
    float bv[16], gv[16], bev[16];
    #pragma unroll
    for (int ni = 0; ni < 16; ++ni) {
      int col = wn1 + ni * 16 + l16;
      bv[ni] = bias1[col]; gv[ni] = g1[col]; bev[ni] = be1[col];
    }
    #pragma unroll
    for (int r = 0; r < 4; ++r) {
      int row = wm1 + quad * 4 + r;
      float s = 0.f, sq = 0.f;
      #pragma unroll
      for (int ni = 0; ni < 16; ++ni) {
        float val = acc1[ni][r] + bv[ni];
        acc1[ni][r] = val; s += val; sq += val * val;
      }
      #pragma unroll
      for (int off = 1; off < 16; off <<= 1) { s += __shfl_xor(s, off, 64); sq += __shfl_xor(sq, off, 64); }
      if (l16 == 0) { lnsum[wni * 32 + row] = s; lnsq[wni * 32 + row] = sq; }
    }
    __syncthreads();
    #pragma unroll
    for (int r = 0; r < 4; ++r) {
      int row = wm1 + quad * 4 + r;
      float tot = lnsum[row] + lnsum[32 + row];
      float tsq = lnsq[row] + lnsq[32 + row];
      float mean = tot * (1.f / 512.f);
      float var = tsq * (1.f / 512.f) - mean * mean;
      float rr = rsqrtf(var + 1e-5f);
      #pragma unroll
      for (int ni = 0; ni < 16; ++ni)
        H[row * 520 + wn1 + ni * 16 + l16] = f2bf(elu((acc1[ni][r] - mean) * rr * gv[ni] + bev[ni]));
    }
  }
  __syncthreads();
  // ---- phase 2: GEMM2 K=512 -> 32x256, LN+ELU -> alpha ----
  unsigned short* B2s = B1s;
  int wm2 = (wave >> 1) * 16, wn2 = (wave & 1) * 128;
  f32x4 acc2[8] = {};
  for (int k0 = 0; k0 < 512; k0 += 32) {
    for (int t = tid; t < 1024; t += 256) {
      int n = t >> 2, c = (t & 3) * 8;
      *(uint4v*)&B2s[n * 40 + c] = *(const uint4v*)(B2t + (size_t)n * 512 + k0 + c);
    }
    __syncthreads();
    bf16x8 a2 = __builtin_bit_cast(bf16x8, *(const uint4v*)&H[(wm2 + l16) * 520 + k0 + quad * 8]);
    #pragma unroll
    for (int ni = 0; ni < 8; ++ni) {
      bf16x8 b2v = __builtin_bit_cast(bf16x8, *(const uint4v*)&B2s[(wn2 + ni * 16 + l16) * 40 + quad * 8]);
      acc2[ni] = __builtin_amdgcn_mfma_f32_16x16x32_bf16(a2, b2v, acc2[ni], 0, 0, 0);
    }
    __syncthreads();
  }
  float bv[8], gv[8], bev[8];
  #pragma unroll
  for (int ni = 0; ni < 8; ++ni) {
    int col = wn2 + ni * 16 + l16;
    bv[ni] = bias2[col]; gv[ni] = g2[col]; bev[ni] = be2[col];
  }
  #pragma unroll
  for (int r = 0; r < 4; ++r) {
    int row = wm2 + quad * 4 + r;
    float s2 = 0.f, q2 = 0.f;
    #pragma unroll
    for (int ni = 0; ni < 8; ++ni) {
      float val = acc2[ni][r] + bv[ni];
      acc2[ni][r] = val; s2 += val; q2 += val * val;
    }
    #pragma unroll
    for (int off = 1; off < 16; off <<= 1) { s2 += __shfl_xor(s2, off, 64); q2 += __shfl_xor(q2, off, 64); }
    if (l16 == 0) { lnsum[wni * 32 + row] = s2; lnsq[wni * 32 + row] = q2; }
  }
  __syncthreads();
  #pragma unroll
  for (int r = 0; r < 4; ++r) {
    int row = wm2 + quad * 4 + r;
    float tot = lnsum[row] + lnsum[32 + row];
    float tsq = lnsq[row] + lnsq[32 + row];
    float mean = tot * (1.f / 256.f);
    float var = tsq * (1.f / 256.f) - mean * mean;
    float rr = rsqrtf(var + 1e-5f);
    size_t ob = (size_t)(el0 + row) * 256;
    #pragma unroll
    for (int ni = 0; ni < 8; ++ni)
      alpha_b[ob + wn2 + ni * 16 + l16] = f2bf(elu((acc2[ni][r] - mean) * rr * gv[ni] + bev[ni]));
  }
}

// ---------------- plain bf16 MFMA GEMM (node GEMMs / stem): optional fp32/bf16 out ----------------
#define APAD 40
__global__ __launch_bounds__(256)
void gemm_mfma(const unsigned short* __restrict__ A, const unsigned short* __restrict__ Bt,
               const float* __restrict__ bias, float* __restrict__ Cf,
               unsigned short* __restrict__ Cb, int M, int Nn, int Kk) {
  __shared__ alignas(16) unsigned short As[128 * APAD];
  __shared__ alignas(16) unsigned short Bs[128 * APAD];
  int tid = threadIdx.x;
  int wave = tid >> 6, lane = tid & 63;
  int quad = lane >> 4, l16 = lane & 15;
  int wm = (wave >> 1) * 64, wn = (wave & 1) * 64;
  int m0 = blockIdx.y * 128, n0 = blockIdx.x * 128;
  f32x4 acc[4][4] = {};
  int srow = tid >> 2;
  int scol = (tid & 3) * 8;
  for (int k0 = 0; k0 < Kk; k0 += 32) {
    #pragma unroll
    for (int h = 0; h < 2; ++h) {
      int r = srow + h * 64;
      int gm = m0 + r;
      uint4v va = {0, 0, 0, 0};
      if (gm < M) va = *(const uint4v*)(A + (size_t)gm * Kk + k0 + scol);
      *(uint4v*)(&As[r * APAD + scol]) = va;
      int gn = n0 + r;
      uint4v vb = *(const uint4v*)(Bt + (size_t)gn * Kk + k0 + scol);
      *(uint4v*)(&Bs[r * APAD + scol]) = vb;
    }
    __syncthreads();
    bf16x8 af[4], bfr[4];
    #pragma unroll
    for (int mi = 0; mi < 4; ++mi)
      af[mi] = __builtin_bit_cast(bf16x8, *(const uint4v*)(&As[(wm + mi * 16 + l16) * APAD + quad * 8]));
    #pragma unroll
    for (int ni = 0; ni < 4; ++ni)
      bfr[ni] = __builtin_bit_cast(bf16x8, *(const uint4v*)(&Bs[(wn + ni * 16 + l16) * APAD + quad * 8]));
    #pragma unroll
    for (int mi = 0; mi < 4; ++mi)
      #pragma unroll
      for (int ni = 0; ni < 4; ++ni)
        acc[mi][ni] = __builtin_amdgcn_mfma_f32_16x16x32_bf16(af[mi], bfr[ni], acc[mi][ni], 0, 0, 0);
    __syncthreads();
  }
  float bvs[4]; int gns[4];
  #pragma unroll
  for (int ni = 0; ni < 4; ++ni) {
    gns[ni] = n0 + wn + ni * 16 + l16;
    bvs[ni] = bias ? bias[gns[ni]] : 0.f;
  }
  #pragma unroll
  for (int mi = 0; mi < 4; ++mi) {
    #pragma unroll
    for (int r = 0; r < 4; ++r) {
      int gm = m0 + wm + mi * 16 + quad * 4 + r;
      if (gm >= M) continue;
      #pragma unroll
      for (int ni = 0; ni < 4; ++ni) {
        float val = acc[mi][ni][r] + bvs[ni];
        if (Cf) Cf[(size_t)gm * Nn + gns[ni]] = val;
        if (Cb) Cb[(size_t)gm * Nn + gns[ni]] = f2bf(val);
      }
    }
  }
}

// ---------------- fp32 tiled GEMM (head only, M=8) ----------------
#define BM0 64
#define BN0 64
#define BK0 16
__global__ __launch_bounds__(256)
void gemm_bias(const float* __restrict__ A, const float* __restrict__ Bw,
               const float* __restrict__ bias, float* __restrict__ C,
               int M, int Nn, int Kk) {
  __shared__ float Asm[BK0][BM0 + 1];
  __shared__ float Bsm[BK0][BN0 + 1];
  int bm = blockIdx.y * BM0, bn = blockIdx.x * BN0;
  int tid = threadIdx.x;
  int tx = tid & 15, ty = tid >> 4;
  float acc[4][4] = {{0.f}};
  for (int k0 = 0; k0 < Kk; k0 += BK0) {
    #pragma unroll
    for (int ii = 0; ii < 4; ++ii) {
      int e = tid + ii * 256;
      int m = e >> 4, k = e & 15;
      int gm = bm + m, gk = k0 + k;
      Asm[k][m] = (gm < M && gk < Kk) ? A[(size_t)gm * Kk + gk] : 0.f;
    }
    #pragma unroll
    for (int ii = 0; ii < 4; ++ii) {
      int e = tid + ii * 256;
      int k = e >> 6, n = e & 63;
      int gk = k0 + k, gn = bn + n;
      Bsm[k][n] = (gk < Kk && gn < Nn) ? Bw[(size_t)gk * Nn + gn] : 0.f;
    }
    __syncthreads();
    #pragma unroll
    for (int kk = 0; kk < BK0; ++kk) {
      float a[4], b[4];
      #pragma unroll
      for (int ii = 0; ii < 4; ++ii) a[ii] = Asm[kk][ty * 4 + ii];
      #pragma unroll
      for (int jj = 0; jj < 4; ++jj) b[jj] = Bsm[kk][tx * 4 + jj];
      #pragma unroll
      for (int ii = 0; ii < 4; ++ii)
        #pragma unroll
        for (int jj = 0; jj < 4; ++jj)
          acc[ii][jj] += a[ii] * b[jj];
    }
    __syncthreads();
  }
  #pragma unroll
  for (int ii = 0; ii < 4; ++ii) {
    int gm = bm + ty * 4 + ii;
    if (gm >= M) continue;
    #pragma unroll
    for (int jj = 0; jj < 4; ++jj) {
      int gn = bn + tx * 4 + jj;
      if (gn >= Nn) continue;
      float vv = acc[ii][jj];
      if (bias) vv += bias[gn];
      C[(size_t)gm * Nn + gn] = vv;
    }
  }
}

// ---------------- LayerNorm + ELU (tail & head) ----------------
__global__ __launch_bounds__(256)
void ln_elu_kernel(const float* __restrict__ in, float* __restrict__ outf,
                   unsigned short* __restrict__ outb,
                   const float* __restrict__ g, const float* __restrict__ bb,
                   int Cn, int do_elu) {
  __shared__ float sdata[4];
  size_t row = blockIdx.x;
  const float* x = in + row * Cn;
  int tid = threadIdx.x;
  float v0 = x[tid];
  float v1 = (Cn == 512) ? x[tid + 256] : 0.f;
  float s = v0 + v1;
  #pragma unroll
  for (int off = 32; off > 0; off >>= 1) s += __shfl_xor(s, off, 64);
  if ((tid & 63) == 0) sdata[tid >> 6] = s;
  __syncthreads();
  float mean = (sdata[0] + sdata[1] + sdata[2] + sdata[3]) / (float)Cn;
  float d0 = v0 - mean;
  float d1 = (Cn == 512) ? (v1 - mean) : 0.f;
  float sq = d0 * d0 + d1 * d1;
  __syncthreads();
  #pragma unroll
  for (int off = 32; off > 0; off >>= 1) sq += __shfl_xor(sq, off, 64);
  if ((tid & 63) == 0) sdata[tid >> 6] = sq;
  __syncthreads();
  float var = (sdata[0] + sdata[1] + sdata[2] + sdata[3]) / (float)Cn;
  float r = rsqrtf(var + 1e-5f);
  float y0 = d0 * r * g[tid] + bb[tid];
  if (do_elu) y0 = elu(y0);
  if (outf) outf[row * Cn + tid] = y0;
  if (outb) outb[row * Cn + tid] = f2bf(y0);
  if (Cn == 512) {
    float y1 = d1 * r * g[tid + 256] + bb[tid + 256];
    if (do_elu) y1 = elu(y1);
    if (outf) outf[row * Cn + tid + 256] = y1;
    if (outb) outb[row * Cn + tid + 256] = f2bf(y1);
  }
}

// ---------------- per-channel softmax over K + weighted aggregation ----------------
__global__ __launch_bounds__(256)
void softmax_agg(const unsigned short* __restrict__ alpha_b,
                 const unsigned short* __restrict__ delta_b,
                 const unsigned short* __restrict__ v_b,
                 const int* __restrict__ neigh,
                 float* __restrict__ agg, int node0) {
  int nl = blockIdx.x;
  int c = threadIdx.x;
  int i = node0 + nl;
  float av[KNN];
  float mx = -3.4e38f;
  #pragma unroll
  for (int k = 0; k < KNN; ++k) {
    av[k] = bf2f(alpha_b[((size_t)nl * KNN + k) * HDIM + c]);
    mx = fmaxf(mx, av[k]);
  }
  float ssum = 0.f;
  #pragma unroll
  for (int k = 0; k < KNN; ++k) { av[k] = expf(av[k] - mx); ssum += av[k]; }
  float inv = 1.f / ssum;
  float acc = 0.f;
  #pragma unroll
  for (int k = 0; k < KNN; ++k) {
    int j = neigh[(size_t)i * KNN + k];
    acc += av[k] * inv * (bf2f(v_b[(size_t)j * HDIM + c]) +
                          bf2f(delta_b[((size_t)nl * KNN + k) * HDIM + c]));
  }
  agg[(size_t)i * HDIM + c] = acc;
}

// ---------------- x += res_alpha[l] * h ; xb = bf16(x) ----------------
__global__ __launch_bounds__(256)
void axpy_res(float* __restrict__ x, unsigned short* __restrict__ xb,
              const float* __restrict__ h, const float* __restrict__ alpha, int l) {
  size_t idx = (size_t)blockIdx.x * 256 + threadIdx.x;
  float nv = x[idx] + alpha[l] * h[idx];
  x[idx] = nv;
  xb[idx] = f2bf(nv);
}

// ---------------- global max pool, two-stage ----------------
__global__ __launch_bounds__(256)
void seg_max_p(const float* __restrict__ h, float* __restrict__ part) {
  int blk = blockIdx.x;
  int b = blk >> 4, ch = blk & 15;
  int c = threadIdx.x;
  const float* base = h + ((size_t)b * PPC + (size_t)ch * 64) * HDIM;
  float m = -3.4e38f;
  for (int p = 0; p < 64; ++p)
    m = fmaxf(m, base[(size_t)p * HDIM + c]);
  part[(size_t)blk * HDIM + c] = m;
}
__global__ __launch_bounds__(256)
void seg_max_f(const float* __restrict__ part, float* __restrict__ pooled) {
  int b = blockIdx.x;
  int c = threadIdx.x;
  float m = -3.4e38f;
  for (int k = 0; k < 16; ++k)
    m = fmaxf(m, part[(size_t)(b * 16 + k) * HDIM + c]);
  pooled[(size_t)b * HDIM + c] = m;
}

extern "C" void kernel_launch(void* const* d_in, const int* in_sizes, int n_in,
                              void* d_out, int out_size, void* d_ws, size_t ws_size,
                              hipStream_t stream) {
  const float* pos       = (const float*)d_in[0];
  const float* ffm_W     = (const float*)d_in[2];
  const float* ffm_b     = (const float*)d_in[3];
  const float* lin_W     = (const float*)d_in[4];
  const float* src_W     = (const float*)d_in[5];
  const float* dst_W     = (const float*)d_in[6];
  const float* pos1_W    = (const float*)d_in[7];
  const float* pos1_b    = (const float*)d_in[8];
  const float* pos_ln1_g = (const float*)d_in[9];
  const float* pos_ln1_b = (const float*)d_in[10];
  const float* pos2_W    = (const float*)d_in[11];
  const float* pos2_b    = (const float*)d_in[12];
  const float* pos_ln2_g = (const float*)d_in[13];
  const float* pos_ln2_b = (const float*)d_in[14];
  const float* att1_W    = (const float*)d_in[15];
  const float* att1_b    = (const float*)d_in[16];
  const float* att_ln1_g = (const float*)d_in[17];
  const float* att_ln1_b = (const float*)d_in[18];
  const float* att2_W    = (const float*)d_in[19];
  const float* att2_b    = (const float*)d_in[20];
  const float* att_ln2_g = (const float*)d_in[21];
  const float* att_ln2_b = (const float*)d_in[22];
  const float* blk_ln_g  = (const float*)d_in[23];
  const float* blk_ln_b  = (const float*)d_in[24];
  const float* blk_W     = (const float*)d_in[25];
  const float* blk_b     = (const float*)d_in[26];
  const float* res_alpha = (const float*)d_in[27];
  const float* r1_W = (const float*)d_in[28]; const float* r1_b = (const float*)d_in[29];
  const float* r2_W = (const float*)d_in[30]; const float* r2_b = (const float*)d_in[31];
  const float* r2_ln_g = (const float*)d_in[32]; const float* r2_ln_b = (const float*)d_in[33];
  const float* r3_W = (const float*)d_in[34]; const float* r3_b = (const float*)d_in[35];
  const float* r3_ln_g = (const float*)d_in[36]; const float* r3_ln_b = (const float*)d_in[37];
  const float* r4_W = (const float*)d_in[38]; const float* r4_b = (const float*)d_in[39];
  float* out = (float*)d_out;

  // ---- workspace carve-up ----
  char* wsp = (char*)d_ws;
  auto alloc = [&](size_t bytes) -> void* {
    void* p = (void*)wsp;
    wsp += (bytes + 255) & ~(size_t)255;
    return p;
  };
  int*            neigh   = (int*)alloc(EDG * sizeof(int));
  float*          rel_f   = (float*)alloc((size_t)EDG * 3 * 4);
  unsigned short* posb    = (unsigned short*)alloc((size_t)NPTS * 32 * 2);
  float*          x       = (float*)alloc((size_t)NPTS * HDIM * 4);
  unsigned short* xb      = (unsigned short*)alloc((size_t)NPTS * HDIM * 2);
  unsigned short* xln_b   = (unsigned short*)alloc((size_t)NPTS * HDIM * 2);
  unsigned short* a_src_b = (unsigned short*)alloc((size_t)NPTS * HDIM * 2);
  unsigned short* a_dst_b = (unsigned short*)alloc((size_t)NPTS * HDIM * 2);
  unsigned short* v_b     = (unsigned short*)alloc((size_t)NPTS * HDIM * 2);
  float*          agg     = (float*)alloc((size_t)NPTS * HDIM * 4);
  float*          segp    = (float*)alloc((size_t)128 * HDIM * 4);
  float*          pooled  = (float*)alloc((size_t)BCL * HDIM * 4);
  float*          hh      = (float*)alloc((size_t)BCL * HDIM * 4);
  unsigned short* ffmt = (unsigned short*)alloc((size_t)HDIM * 32 * 2);
  unsigned short* r1t  = (unsigned short*)alloc((size_t)HDIM * HDIM * 2);
  unsigned short *lint[NL], *srct[NL], *dstt[NL], *blkt[NL];
  unsigned short *pos2t[NL], *att1t[NL], *att2t[NL];
  for (int l = 0; l < NL; ++l) {
    lint[l]  = (unsigned short*)alloc((size_t)HDIM * HDIM * 2);
    srct[l]  = (unsigned short*)alloc((size_t)HDIM * HDIM * 2);
    dstt[l]  = (unsigned short*)alloc((size_t)HDIM * HDIM * 2);
    blkt[l]  = (unsigned short*)alloc((size_t)HDIM * HDIM * 2);
    pos2t[l] = (unsigned short*)alloc((size_t)HDIM * HD2 * 2);
    att1t[l] = (unsigned short*)alloc((size_t)HD2 * HDIM * 2);
    att2t[l] = (unsigned short*)alloc((size_t)HDIM * HD2 * 2);
  }
  // chunked edge buffers: delta + alpha (bf16)
  size_t used = (size_t)(wsp - (char*)d_ws);
  size_t avail = (ws_size > used) ? (ws_size - used) : 0;
  size_t per_node = (size_t)KNN * (HDIM * 2 * 2) + 1024;
  int Nc = (int)(avail / per_node);
  if (Nc > NPTS) Nc = NPTS;
  Nc &= ~15;                 // ec multiple of 320 -> divisible by 32
  if (Nc < 16) Nc = 16;
  unsigned short* delta_b = (unsigned short*)alloc((size_t)Nc * KNN * HDIM * 2);
  unsigned short* alpha_b = (unsigned short*)alloc((size_t)Nc * KNN * HDIM * 2);

  auto mgemm = [&](const unsigned short* A, const unsigned short* Bt, const float* bias,
                   float* Cf, unsigned short* Cb, int M, int Nn, int Kk) {
    dim3 g(Nn / 128, (M + 127) / 128);
    gemm_mfma<<<g, dim3(256), 0, stream>>>(A, Bt, bias, Cf, Cb, M, Nn, Kk);
  };
  auto fgemm = [&](const float* A, const float* Bw, const float* bias, float* Cp,
                   int M, int Nn, int Kk) {
    dim3 g((Nn + BN0 - 1) / BN0, (M + BM0 - 1) / BM0);
    gemm_bias<<<g, dim3(256), 0, stream>>>(A, Bw, bias, Cp, M, Nn, Kk);
  };

  // ---- weight prep ----
  transpose_w<<<HDIM, 256, 0, stream>>>(ffm_W, ffmt, 3, HDIM, 32);
  transpose_w<<<HDIM, 256, 0, stream>>>(r1_W, r1t, HDIM, HDIM, HDIM);
  for (int l = 0; l < NL; ++l) {
    transpose_w<<<HDIM, 256, 0, stream>>>(lin_W + (size_t)l * HDIM * HDIM, lint[l], HDIM, HDIM, HDIM);
    transpose_w<<<HDIM, 256, 0, stream>>>(src_W + (size_t)l * HDIM * HDIM, srct[l], HDIM, HDIM, HDIM);
    transpose_w<<<HDIM, 256, 0, stream>>>(dst_W + (size_t)l * HDIM * HDIM, dstt[l], HDIM, HDIM, HDIM);
    transpose_w<<<HDIM, 256, 0, stream>>>(blk_W + (size_t)l * HDIM * HDIM, blkt[l], HDIM, HDIM, HDIM);
    transpose_w<<<HDIM, 256, 0, stream>>>(pos2_W + (size_t)l * HD2 * HDIM, pos2t[l], HD2, HDIM, HD2);
    transpose_w<<<HD2, 256, 0, stream>>>(att1_W + (size_t)l * HDIM * HD2, att1t[l], HDIM, HD2, HDIM);
    transpose_w<<<HDIM, 256, 0, stream>>>(att2_W + (size_t)l * HD2 * HDIM, att2t[l], HD2, HDIM, HD2);
  }

  // ---- graph + stem ----
  knn_wave<<<NPTS / 4, 256, 0, stream>>>(pos, neigh, rel_f);
  prep_pos<<<NPTS * 32 / 256, 256, 0, stream>>>(pos, posb);
  mgemm(posb, ffmt, ffm_b, x, xb, NPTS, HDIM, 32);

  // ---- transformer layers ----
  for (int l = 0; l < NL; ++l) {
    mgemm(xb, srct[l], nullptr, nullptr, a_src_b, NPTS, HDIM, HDIM);
    mgemm(xb, dstt[l], nullptr, nullptr, a_dst_b, NPTS, HDIM, HDIM);
    mgemm(xb, lint[l], nullptr, nullptr, v_b,     NPTS, HDIM, HDIM);

    for (int n0 = 0; n0 < NPTS; n0 += Nc) {
      int nc = (Nc < NPTS - n0) ? Nc : (NPTS - n0);
      int ec = nc * KNN;
      pos_fused<<<ec / 32, 256, 0, stream>>>(
          rel_f, pos1_W + (size_t)l * 3 * HD2, pos1_b + (size_t)l * HD2,
          pos_ln1_g + (size_t)l * HD2, pos_ln1_b + (size_t)l * HD2,
          pos2t[l], pos2_b + (size_t)l * HDIM,
          pos_ln2_g + (size_t)l * HDIM, pos_ln2_b + (size_t)l * HDIM,
          delta_b, n0 * KNN);
      attn_fused<<<ec / 32, 256, 0, stream>>>(
          a_dst_b, a_src_b, delta_b, neigh,
          att1t[l], att1_b + (size_t)l * HD2,
          att_ln1_g + (size_t)l * HD2, att_ln1_b + (size_t)l * HD2,
          att2t[l], att2_b + (size_t)l * HDIM,
          att_ln2_g + (size_t)l * HDIM, att_ln2_b + (size_t)l * HDIM,
          alpha_b, n0 * KNN);
      softmax_agg<<<nc, 256, 0, stream>>>(alpha_b, delta_b, v_b, neigh, agg, n0);
    }
    ln_elu_kernel<<<NPTS, 256, 0, stream>>>(agg, nullptr, xln_b,
                                            blk_ln_g + (size_t)l * HDIM, blk_ln_b + (size_t)l * HDIM, HDIM, 1);
    mgemm(xln_b, blkt[l], blk_b + (size_t)l * HDIM, agg, nullptr, NPTS, HDIM, HDIM);
    axpy_res<<<(NPTS * HDIM) / 256, 256, 0, stream>>>(x, xb, agg, res_alpha, l);
  }

  // ---- regression head ----
  mgemm(xb, r1t, r1_b, agg, nullptr, NPTS, HDIM, HDIM);
  seg_max_p<<<128, 256, 0, stream>>>(agg, segp);
  seg_max_f<<<BCL, 256, 0, stream>>>(segp, pooled);
  fgemm(pooled, r2_W, r2_b, hh, BCL, HDIM, HDIM);
  ln_elu_kernel<<<BCL, 256, 0, stream>>>(hh, hh, nullptr, r2_ln_g, r2_ln_b, HDIM, 1);
  fgemm(hh, r3_W, r3_b, pooled, BCL, HDIM, HDIM);
  ln_elu_kernel<<<BCL, 256, 0, stream>>>(pooled, pooled, nullptr, r3_ln_g, r3_ln_b, HDIM, 1);
  fgemm(pooled, r4_W, r4_b, out, BCL, NCOMP, HDIM);
}